// Round 3
// baseline (43859.485 us; speedup 1.0000x reference)
//
#include <hip/hip_runtime.h>
#include <hip/hip_fp16.h>
#include <hip/hip_cooperative_groups.h>

namespace cg = cooperative_groups;

#define BB   32
#define TENC 256
#define EE   512
#define TDEC 200
#define NM   80
#define HH   1024
#define AA   128
#define GG   4096
#define K1   1792   // x(256)|ctx(512)|h1(1024)
#define K2   2048   // h1|h2

typedef _Float16 h8v  __attribute__((ext_vector_type(8)));
typedef float    f32x4 __attribute__((ext_vector_type(4)));

__device__ __forceinline__ float sigf(float x){ return 1.0f/(1.0f + __expf(-x)); }
__device__ __forceinline__ float tanhfast(float x){ return 1.0f - 2.0f/(1.0f + __expf(2.0f*x)); }

// ---------------- precompute kernels ----------------

__global__ void k_zero(float* __restrict__ p, int n){
    int i = blockIdx.x*blockDim.x + threadIdx.x;
    if(i < n) p[i] = 0.f;
}

__global__ void k_cvt_half(const float* __restrict__ src, __half* __restrict__ dst, int n){
    int i = blockIdx.x*blockDim.x + threadIdx.x;
    int stride = gridDim.x*blockDim.x;
    for(; i<n; i+=stride) dst[i] = __float2half(src[i]);
}

// transpose fp32 src[k][c] -> fp16 dst[p][kOff+k]; pack=1 remaps c (gate*1024+cell) -> p=cell*4+gate
__global__ __launch_bounds__(256) void k_transpose2(const float* __restrict__ src,
                                                    _Float16* __restrict__ dst,
                                                    int K, int C, int dstStride, int kOff, int pack){
    __shared__ float tile[32][33];
    const int tid = threadIdx.x;
    const int c0 = blockIdx.x*32, k0 = blockIdx.y*32;
    const int cl = tid & 31, r8 = tid >> 5;
    #pragma unroll
    for(int i=0;i<4;i++){
        const int k = k0 + r8 + i*8;
        if(k < K && c0+cl < C) tile[r8 + i*8][cl] = src[(size_t)k*C + c0 + cl];
    }
    __syncthreads();
    const int kl = tid & 31, c8 = tid >> 5;
    #pragma unroll
    for(int i=0;i<4;i++){
        const int c = c0 + c8 + i*8;
        if(c < C && k0+kl < K){
            const int p = pack ? ((c & 1023)*4 + (c >> 10)) : c;
            dst[(size_t)p*dstStride + kOff + k0 + kl] = (_Float16)tile[kl][c8 + i*8];
        }
    }
}

// Rearrange WT fp16 [P=4096][K] into MFMA B-fragment order:
// WF[((ct*(K/32)+kc)*64 + lane)*8 + i] = WT[(ct*16 + (lane&15))*K + kc*32 + (lane>>4)*8 + i]
__global__ __launch_bounds__(256) void k_wfrag(const _Float16* __restrict__ WT,
                                               _Float16* __restrict__ WF, int K){
    const int tid = threadIdx.x;
    const int l = tid & 63, f = tid >> 6;
    const int ct = blockIdx.y;
    const int kc = blockIdx.x*4 + f;
    const h8v v = *(const h8v*)(WT + (size_t)(ct*16 + (l & 15))*K + kc*32 + ((l >> 4) << 3));
    *(h8v*)(WF + ((size_t)(ct*(K >> 5) + kc)*64 + l)*8) = v;
}

__global__ __launch_bounds__(128) void k_proc_enc(const float* __restrict__ inputs,
                                                  const float* __restrict__ Wenc,
                                                  __half* __restrict__ pe_h){
    const int row = blockIdx.x;
    const int a   = threadIdx.x;
    const float* in = inputs + (size_t)row*EE;
    float acc = 0.f;
    for(int k=0;k<EE;k++) acc = fmaf(in[k], Wenc[k*AA + a], acc);
    pe_h[(size_t)row*AA + a] = __float2half(acc);
}

__global__ __launch_bounds__(320) void k_pip(const float* __restrict__ inputs,
                                             const float* __restrict__ Wp_c,
                                             __half* __restrict__ PIP){
    const int b = blockIdx.x >> 6, t4 = (blockIdx.x & 63)*4;
    __shared__ float xs[4*EE];
    const int tid = threadIdx.x;
    for(int i=tid; i<4*EE; i+=320) xs[i] = inputs[((size_t)b*TENC + t4)*EE + i];
    __syncthreads();
    const int tl = tid/80, m = tid%80;
    float acc = 0.f;
    for(int k=0;k<EE;k++) acc = fmaf(xs[tl*EE + k], Wp_c[k*NM + m], acc);
    PIP[((size_t)b*TENC + t4 + tl)*NM + m] = __float2half(acc);
}

// prenet for all t -> fp16 XS1h rows [t][b][0:256] (row stride K1)
__global__ __launch_bounds__(256) void k_prenet(const float* __restrict__ pmels,
                                                const float* __restrict__ pw1, const float* __restrict__ pb1,
                                                const float* __restrict__ pw2, const float* __restrict__ pb2,
                                                _Float16* __restrict__ XS1h){
    const int t = blockIdx.x;
    __shared__ float pm[BB*NM];
    __shared__ float h1s[BB*256];
    const int tid = threadIdx.x;
    for(int el=tid; el<BB*NM; el+=256){
        const int b = el/NM, m = el%NM;
        pm[el] = (t==0) ? 0.f : pmels[(size_t)(b*NM + m)*TDEC + (t-1)];
    }
    __syncthreads();
    const int a = tid;
    float acc[BB];
    #pragma unroll
    for(int b=0;b<BB;b++) acc[b]=0.f;
    for(int m=0;m<NM;m++){
        const float w = pw1[m*256 + a];
        #pragma unroll
        for(int b=0;b<BB;b++) acc[b] = fmaf(pm[b*NM+m], w, acc[b]);
    }
    {
        const float bias = pb1[a];
        for(int b=0;b<BB;b++) h1s[b*256+a] = fmaxf(acc[b]+bias, 0.f);
    }
    __syncthreads();
    #pragma unroll
    for(int b=0;b<BB;b++) acc[b]=0.f;
    for(int k=0;k<256;k++){
        const float w = pw2[k*256 + a];
        #pragma unroll
        for(int b=0;b<BB;b++) acc[b] = fmaf(h1s[b*256+k], w, acc[b]);
    }
    {
        const float bias = pb2[a];
        #pragma unroll
        for(int b=0;b<BB;b++)
            XS1h[((size_t)t*BB + b)*K1 + a] = (_Float16)fmaxf(acc[b]+bias, 0.f);
    }
}

__global__ void k_mloc(const float* __restrict__ conv_w, const float* __restrict__ conv_b,
                       const float* __restrict__ W_loc, float* __restrict__ Mloc, float* __restrict__ cbp){
    const int a = threadIdx.x;
    for(int d=0; d<31; d++){
        float s = 0.f;
        for(int ch=0; ch<32; ch++) s = fmaf(conv_w[ch*31 + d], W_loc[ch*AA + a], s);
        Mloc[d*AA + a] = s;
    }
    float s = 0.f;
    for(int ch=0; ch<32; ch++) s = fmaf(conv_b[ch], W_loc[ch*AA + a], s);
    cbp[a] = s;
}

// ---------------- fused decode (cooperative) ----------------

// LSTM phase: 256 blocks x 512 threads. 8 waves = 8 K-slices; each wave does both
// 16-row M-tiles with ONE B-fragment load (B read once). part: [8 kw][32 rows][18].
template<int K>
__device__ __forceinline__ void lstm_phase(
    const _Float16* __restrict__ XSh, const _Float16* __restrict__ WF,
    const float* __restrict__ bias, float* __restrict__ cst,
    _Float16* hA, int strideA, int offA,
    _Float16* hB, int strideB, int offB,
    float* hF, float* part, int tid, int bid)
{
    constexpr int KCN = K/256;          // fragments per wave
    const int l = tid & 63, kw = tid >> 6;
    f32x4 accL = {0.f,0.f,0.f,0.f}, accH = {0.f,0.f,0.f,0.f};
    const int r = l & 15;
    const _Float16* aptr = XSh + (size_t)r*K + kw*KCN*32 + ((l >> 4) << 3);
    const _Float16* bptr = WF + ((size_t)(bid*(K >> 5) + kw*KCN)*64 + l)*8;
    #pragma unroll
    for(int kc=0; kc<KCN; kc++){
        const h8v b8 = *(const h8v*)(bptr + (size_t)kc*512);
        const h8v aL = *(const h8v*)(aptr + (size_t)kc*32);
        const h8v aH = *(const h8v*)(aptr + (size_t)16*K + kc*32);
        accL = __builtin_amdgcn_mfma_f32_16x16x32_f16(aL, b8, accL, 0, 0, 0);
        accH = __builtin_amdgcn_mfma_f32_16x16x32_f16(aH, b8, accH, 0, 0, 0);
    }
    // D layout: col = l&15, row(tile) = (l>>4)*4 + j
    {
        const int r0 = (l >> 4) << 2, c = l & 15;
        #pragma unroll
        for(int j=0;j<4;j++){
            part[(kw*32 + r0 + j)*18 + c]      = accL[j];
            part[(kw*32 + 16 + r0 + j)*18 + c] = accH[j];
        }
    }
    __syncthreads();
    if(tid < 128){
        const int b = tid & 31, cl = tid >> 5;
        float g[4];
        #pragma unroll
        for(int gi=0; gi<4; gi++){
            const int c2 = cl*4 + gi;
            float s = 0.f;
            #pragma unroll
            for(int q=0;q<8;q++) s += part[(q*32 + b)*18 + c2];
            const int p = bid*16 + c2;           // packed col = cell*4 + gate
            g[gi] = s + bias[(p & 3)*HH + (p >> 2)];
        }
        const int cell = bid*4 + cl;
        const int ci = cell*BB + b;
        const float cn = sigf(g[1])*cst[ci] + sigf(g[0])*tanhfast(g[2]);
        cst[ci] = cn;
        const float hv = sigf(g[3])*tanhfast(cn);
        hA[(size_t)b*strideA + offA + cell] = (_Float16)hv;
        if(hB) hB[(size_t)b*strideB + offB + cell] = (_Float16)hv;
        if(hF) hF[(size_t)b*HH + cell] = hv;
    }
}

__global__ __launch_bounds__(512) void k_decode(
    _Float16* __restrict__ XS1h, _Float16* __restrict__ XS2h,
    const _Float16* __restrict__ W1F, const _Float16* __restrict__ W2F,
    const float* __restrict__ bl1, const float* __restrict__ bl2,
    float* __restrict__ c1, float* __restrict__ c2,
    const _Float16* __restrict__ WqT, const float* __restrict__ cbp,
    const float* __restrict__ Mloc, const float* __restrict__ ve,
    float* __restrict__ awc, const __half* __restrict__ pe,
    float* __restrict__ e_ws,
    const __half* __restrict__ inputs_h, const __half* __restrict__ PIP,
    const _Float16* __restrict__ WohT, const float* __restrict__ bp,
    float* __restrict__ h2f, float* __restrict__ out)
{
    cg::grid_group gg = cg::this_grid();
    const int tid = threadIdx.x, bid = blockIdx.x;

    __shared__ float s_ml[31*AA];      // persistent across all steps
    __shared__ float s_ves[AA];
    __shared__ float s_part[8*32*18];  // lstm partials; aliased as ctxred in attn phase
    __shared__ float s_h2s[1024];
    __shared__ float s_qc[4*AA];
    __shared__ float s_qf[AA];
    __shared__ float s_awin[64];
    __shared__ float s_ep[16*32];
    __shared__ float s_aw[TENC];
    __shared__ float s_red1[320];
    __shared__ float s_red2[320];
    __shared__ float s_sred[8];

    for(int i=tid; i<31*AA; i+=512) s_ml[i] = Mloc[i];
    if(tid < AA) s_ves[tid] = ve[tid];
    __syncthreads();

    for(int t=0; t<TDEC; t++){
        const int p = t & 1;
        const _Float16* x1c = XS1h + (size_t)t*BB*K1;
        _Float16* x1n = XS1h + (size_t)(t+1)*BB*K1;
        _Float16* x2p = XS2h + (size_t)p*BB*K2;
        _Float16* x2n = XS2h + (size_t)(1-p)*BB*K2;

        // ---- phase 1: LSTM1 ----
        lstm_phase<K1>(x1c, W1F, bl1, c1,
                       x2p, K2, 0,          // h1 -> XS2h[p][b][0:1024]
                       x1n, K1, 768,        // h1 -> next XS1h row
                       (float*)nullptr, s_part, tid, bid);
        gg.sync();

        // ---- phase 2: LSTM2 ----
        lstm_phase<K2>(x2p, W2F, bl2, c2,
                       x2n, K2, 1024,       // h2 -> XS2h[1-p][b][1024:2048]
                       (_Float16*)nullptr, 0, 0,
                       h2f, s_part, tid, bid);
        gg.sync();

        // ---- phase 3: q + energies (block = b*8+ts, 32-t slice) ----
        {
            const int b = bid >> 3, ts = bid & 7;
            const int t0 = ts*32;
            for(int i=tid; i<1024; i+=512) s_h2s[i] = h2f[(size_t)b*HH + i];
            if(tid < 62){
                const int g = t0 - 15 + tid;
                s_awin[tid] = (g>=0 && g<TENC) ? awc[b*TENC+g] : 0.f;
            }
            __syncthreads();
            {   // q[a] = h2 . WqT[a][:], split K 4-ways
                const int a = tid & 127, tp = tid >> 7;
                float qa = 0.f;
                const _Float16* wq = WqT + (size_t)a*HH + tp*256;
                const float* hs = s_h2s + tp*256;
                for(int kb=0; kb<256; kb+=8){
                    const h8v w8 = *(const h8v*)(wq + kb);
                    #pragma unroll
                    for(int i2=0;i2<8;i2++) qa = fmaf((float)w8[i2], hs[kb+i2], qa);
                }
                s_qc[tp*AA + a] = qa;
            }
            __syncthreads();
            if(tid < AA) s_qf[tid] = s_qc[tid] + s_qc[AA+tid] + s_qc[2*AA+tid] + s_qc[3*AA+tid] + cbp[tid];
            __syncthreads();
            {   // energies: thread (tl 32, aq 16) covers 8 a for t0+tl
                const int tl = tid & 31, aq = tid >> 5;
                const int a0 = aq*8;
                const int tt = t0 + tl;
                float s[8];
                const __half* pp = pe + ((size_t)(b*TENC + tt))*AA + a0;
                #pragma unroll
                for(int j=0;j<8;j++) s[j] = s_qf[a0+j] + __half2float(pp[j]);
                for(int d=0;d<31;d++){
                    const float w = s_awin[tl+d];
                    #pragma unroll
                    for(int j=0;j<8;j++) s[j] = fmaf(w, s_ml[d*AA + a0 + j], s[j]);
                }
                float es = 0.f;
                #pragma unroll
                for(int j=0;j<8;j++) es = fmaf(tanhfast(s[j]), s_ves[a0+j], es);
                s_ep[aq*32 + tl] = es;
            }
            __syncthreads();
            if(tid < 32){
                float e = 0.f;
                #pragma unroll
                for(int q=0;q<16;q++) e += s_ep[q*32 + tid];
                e_ws[b*TENC + t0 + tid] = e;
            }
        }
        gg.sync();

        // ---- phase 4: softmax + awc + ctx + output (blocks 0..31) ----
        if(bid < BB){
            const int b = bid;
            float* ctxred = s_part;   // aliased: lstm partials dead here
            for(int i=tid; i<1024; i+=512) s_h2s[i] = h2f[(size_t)b*HH + i];
            float e = -1e30f;
            if(tid < 256) e = e_ws[b*TENC + tid];
            float m = e;
            #pragma unroll
            for(int o=32;o>=1;o>>=1) m = fmaxf(m, __shfl_xor(m, o));
            if((tid&63)==0 && tid<256) s_sred[tid>>6] = m;
            __syncthreads();
            m = fmaxf(fmaxf(s_sred[0],s_sred[1]), fmaxf(s_sred[2],s_sred[3]));
            const float pv = (tid<256) ? __expf(e - m) : 0.f;
            float sum = pv;
            #pragma unroll
            for(int o=32;o>=1;o>>=1) sum += __shfl_xor(sum, o);
            if((tid&63)==0 && tid<256) s_sred[4+(tid>>6)] = sum;
            __syncthreads();
            sum = s_sred[4]+s_sred[5]+s_sred[6]+s_sred[7];
            if(tid < 256){
                const float awv = pv/sum;
                s_aw[tid] = awv;
                awc[b*TENC + tid] += awv;
            }
            __syncthreads();
            // ctx: thread (ch8 = tid&63 -> 8 channels, tq = tid>>6 -> t-slice) + LDS reduce
            {
                const int ch8 = tid & 63, tq = tid >> 6;
                const __half* ib = inputs_h + (size_t)b*TENC*EE + ch8*8;
                float a_[8];
                #pragma unroll
                for(int j=0;j<8;j++) a_[j]=0.f;
                for(int tt=tq; tt<TENC; tt+=8){
                    const float wv = s_aw[tt];
                    const h8v x8 = *(const h8v*)(ib + (size_t)tt*EE);
                    #pragma unroll
                    for(int j=0;j<8;j++) a_[j] = fmaf(wv, (float)x8[j], a_[j]);
                }
                #pragma unroll
                for(int j=0;j<8;j++) ctxred[tq*512 + ch8*8 + j] = a_[j];
            }
            __syncthreads();
            {
                float s = 0.f;
                #pragma unroll
                for(int q=0;q<8;q++) s += ctxred[q*512 + tid];
                x1n[(size_t)b*K1 + 256 + tid] = (_Float16)s;
            }
            // out projection: tid<320: kh = tid/80 quarter-chunks
            if(tid < 320){
                const int m2 = tid % 80, kh = tid / 80;
                float s1 = 0.f;
                const _Float16* wo = WohT + (size_t)m2*HH + kh*256;
                const float* hs = s_h2s + kh*256;
                for(int kb=0; kb<256; kb+=8){
                    const h8v w8 = *(const h8v*)(wo + kb);
                    #pragma unroll
                    for(int i2=0;i2<8;i2++) s1 = fmaf((float)w8[i2], hs[kb+i2], s1);
                }
                s_red1[kh*80 + m2] = s1;
                float s2 = 0.f;
                const __half* pp = PIP + ((size_t)(b*TENC) + kh*64)*NM + m2;
                const float* awp = s_aw + kh*64;
                for(int tt=0; tt<64; tt++) s2 = fmaf(awp[tt], __half2float(pp[(size_t)tt*NM]), s2);
                s_red2[kh*80 + m2] = s2;
            }
            __syncthreads();
            if(tid < NM){
                const float o = s_red1[tid]+s_red1[80+tid]+s_red1[160+tid]+s_red1[240+tid]
                              + s_red2[tid]+s_red2[80+tid]+s_red2[160+tid]+s_red2[240+tid] + bp[tid];
                out[((size_t)t*BB + b)*NM + tid] = o;
            }
        }
        gg.sync();
    }
}

// ---------------- host ----------------

extern "C" void kernel_launch(void* const* d_in, const int* in_sizes, int n_in,
                              void* d_out, int out_size, void* d_ws, size_t ws_size,
                              hipStream_t stream)
{
    const float* inputs = (const float*)d_in[0];
    const float* pmels  = (const float*)d_in[1];
    const float* W_enc  = (const float*)d_in[2];
    const float* W_q    = (const float*)d_in[3];
    const float* conv_w = (const float*)d_in[4];
    const float* conv_b = (const float*)d_in[5];
    const float* W_loc  = (const float*)d_in[6];
    const float* v_e    = (const float*)d_in[7];
    const float* pw1    = (const float*)d_in[8];
    const float* pb1    = (const float*)d_in[9];
    const float* pw2    = (const float*)d_in[10];
    const float* pb2    = (const float*)d_in[11];
    const float* Wi1    = (const float*)d_in[12];
    const float* Wh1    = (const float*)d_in[13];
    const float* bl1    = (const float*)d_in[14];
    const float* Wi2    = (const float*)d_in[15];
    const float* Wh2    = (const float*)d_in[16];
    const float* bl2    = (const float*)d_in[17];
    const float* Wp     = (const float*)d_in[18];
    const float* bp     = (const float*)d_in[19];
    float* out = (float*)d_out;
    (void)in_sizes; (void)n_in; (void)out_size; (void)ws_size;

    char* ws = (char*)d_ws;
    size_t off = 0;
    auto carve = [&](size_t bytes)->char* {
        char* p = ws + off;
        off += (bytes + 255) & ~(size_t)255;
        return p;
    };
    __half*    inputs_h = (__half*)   carve((size_t)BB*TENC*EE*2);
    __half*    pe_h     = (__half*)   carve((size_t)BB*TENC*AA*2);
    __half*    PIP      = (__half*)   carve((size_t)BB*TENC*NM*2);
    _Float16*  XS1h     = (_Float16*) carve((size_t)(TDEC+1)*BB*K1*2);
    _Float16*  XS2h     = (_Float16*) carve((size_t)2*BB*K2*2);
    _Float16*  WA       = (_Float16*) carve((size_t)GG*K2*2);   // W2T, later reused as W1F
    _Float16*  WB       = (_Float16*) carve((size_t)GG*K1*2);   // W1T
    _Float16*  W2F      = (_Float16*) carve((size_t)GG*K2*2);
    _Float16*  WqT      = (_Float16*) carve((size_t)AA*HH*2);
    _Float16*  WohT     = (_Float16*) carve((size_t)NM*HH*2);
    // zeroed block: c1 | c2 | awc
    const int NZ = HH*BB + HH*BB + BB*TENC;
    float* zblk = (float*)carve((size_t)NZ*4);
    float* c1  = zblk;
    float* c2  = c1 + HH*BB;
    float* awc = c2 + HH*BB;
    float* h2f  = (float*)carve((size_t)BB*HH*4);
    float* e_ws = (float*)carve((size_t)BB*TENC*4);
    float* Mloc = (float*)carve((size_t)31*AA*4);
    float* cbp  = (float*)carve((size_t)AA*4);
    _Float16* W1F = WA;   // alias: W2T dead once W2F is built

    // ---- one-time precompute (per launch) ----
    k_zero<<<(NZ+255)/256,256,0,stream>>>(zblk, NZ);
    k_zero<<<(2*BB*K2/2+255)/256,256,0,stream>>>((float*)XS2h, 2*BB*K2/2);
    k_zero<<<(BB*K1/2+255)/256,256,0,stream>>>((float*)XS1h, BB*K1/2);
    k_cvt_half<<<2048,256,0,stream>>>(inputs, inputs_h, BB*TENC*EE);
    k_proc_enc<<<BB*TENC,128,0,stream>>>(inputs, W_enc, pe_h);
    k_prenet<<<TDEC,256,0,stream>>>(pmels, pw1,pb1,pw2,pb2, XS1h);
    k_mloc<<<1,128,0,stream>>>(conv_w, conv_b, W_loc, Mloc, cbp);
    k_transpose2<<<dim3(GG/32, 1024/32),256,0,stream>>>(Wi2, WA, 1024, GG, K2, 0,    1);
    k_transpose2<<<dim3(GG/32, 1024/32),256,0,stream>>>(Wh2, WA, 1024, GG, K2, 1024, 1);
    k_wfrag<<<dim3(K2/128, GG/16),256,0,stream>>>(WA, W2F, K2);
    k_transpose2<<<dim3(GG/32,  768/32),256,0,stream>>>(Wi1, WB, 768,  GG, K1, 0,    1);
    k_transpose2<<<dim3(GG/32, 1024/32),256,0,stream>>>(Wh1, WB, 1024, GG, K1, 768,  1);
    k_wfrag<<<dim3(K1/128, GG/16),256,0,stream>>>(WB, W1F, K1);
    k_transpose2<<<dim3(AA/32, 1024/32),256,0,stream>>>(W_q, WqT, 1024, AA, HH, 0,   0);
    k_transpose2<<<dim3(3,     1024/32),256,0,stream>>>(Wp,  WohT, 1024, NM, HH, 0,  0);
    k_pip<<<BB*64,320,0,stream>>>(inputs, Wp + (size_t)HH*NM, PIP);

    // ---- fused sequential decode: ONE cooperative kernel ----
    {
        void* ka[21];
        ka[0]  = (void*)&XS1h;
        ka[1]  = (void*)&XS2h;
        ka[2]  = (void*)&W1F;
        ka[3]  = (void*)&W2F;
        ka[4]  = (void*)&bl1;
        ka[5]  = (void*)&bl2;
        ka[6]  = (void*)&c1;
        ka[7]  = (void*)&c2;
        ka[8]  = (void*)&WqT;
        ka[9]  = (void*)&cbp;
        ka[10] = (void*)&Mloc;
        ka[11] = (void*)&v_e;
        ka[12] = (void*)&awc;
        ka[13] = (void*)&pe_h;
        ka[14] = (void*)&e_ws;
        ka[15] = (void*)&inputs_h;
        ka[16] = (void*)&PIP;
        ka[17] = (void*)&WohT;
        ka[18] = (void*)&bp;
        ka[19] = (void*)&h2f;
        ka[20] = (void*)&out;
        hipLaunchCooperativeKernel((const void*)k_decode, dim3(256), dim3(512),
                                   ka, 0, stream);
    }
}

// Round 4
// 19168.573 us; speedup vs baseline: 2.2881x; 2.2881x over previous
//
#include <hip/hip_runtime.h>
#include <hip/hip_fp16.h>

#define BB   32
#define TENC 256
#define EE   512
#define TDEC 200
#define NM   80
#define HH   1024
#define AA   128
#define GG   4096
#define K1   1792   // x(256)|ctx(512)|h1(1024)
#define K2   2048   // h1|h2

typedef _Float16 h8v  __attribute__((ext_vector_type(8)));
typedef float    f32x4 __attribute__((ext_vector_type(4)));

__device__ __forceinline__ float sigf(float x){ return 1.0f/(1.0f + __expf(-x)); }
__device__ __forceinline__ float tanhfast(float x){ return 1.0f - 2.0f/(1.0f + __expf(2.0f*x)); }

__device__ __forceinline__ unsigned short h2b(float f){
    _Float16 h = (_Float16)f; unsigned short u; __builtin_memcpy(&u, &h, 2); return u;
}
__device__ __forceinline__ float b2f(unsigned short u){
    _Float16 h; __builtin_memcpy(&h, &u, 2); return (float)h;
}
__device__ __forceinline__ void st64(unsigned long long* p, unsigned long long v){
    __hip_atomic_store(p, v, __ATOMIC_RELAXED, __HIP_MEMORY_SCOPE_AGENT);
}
__device__ __forceinline__ void st32(unsigned int* p, unsigned int v){
    __hip_atomic_store(p, v, __ATOMIC_RELAXED, __HIP_MEMORY_SCOPE_AGENT);
}
__device__ __forceinline__ unsigned long long ld64(const unsigned long long* p){
    return __hip_atomic_load(p, __ATOMIC_RELAXED, __HIP_MEMORY_SCOPE_AGENT);
}
__device__ __forceinline__ unsigned int ld32(const unsigned int* p){
    return __hip_atomic_load(p, __ATOMIC_RELAXED, __HIP_MEMORY_SCOPE_AGENT);
}

// ---------------- precompute kernels ----------------

__global__ void k_zero(float* __restrict__ p, int n){
    int i = blockIdx.x*blockDim.x + threadIdx.x;
    if(i < n) p[i] = 0.f;
}

__global__ void k_cvt_half(const float* __restrict__ src, __half* __restrict__ dst, int n){
    int i = blockIdx.x*blockDim.x + threadIdx.x;
    int stride = gridDim.x*blockDim.x;
    for(; i<n; i+=stride) dst[i] = __float2half(src[i]);
}

// transpose fp32 src[k][c] -> fp16 dst[p][kOff+k]; pack=1 remaps c (gate*1024+cell) -> p=cell*4+gate
__global__ __launch_bounds__(256) void k_transpose2(const float* __restrict__ src,
                                                    _Float16* __restrict__ dst,
                                                    int K, int C, int dstStride, int kOff, int pack){
    __shared__ float tile[32][33];
    const int tid = threadIdx.x;
    const int c0 = blockIdx.x*32, k0 = blockIdx.y*32;
    const int cl = tid & 31, r8 = tid >> 5;
    #pragma unroll
    for(int i=0;i<4;i++){
        const int k = k0 + r8 + i*8;
        if(k < K && c0+cl < C) tile[r8 + i*8][cl] = src[(size_t)k*C + c0 + cl];
    }
    __syncthreads();
    const int kl = tid & 31, c8 = tid >> 5;
    #pragma unroll
    for(int i=0;i<4;i++){
        const int c = c0 + c8 + i*8;
        if(c < C && k0+kl < K){
            const int p = pack ? ((c & 1023)*4 + (c >> 10)) : c;
            dst[(size_t)p*dstStride + kOff + k0 + kl] = (_Float16)tile[kl][c8 + i*8];
        }
    }
}

// Rearrange WT fp16 [P=4096][K] into MFMA B-fragment order.
__global__ __launch_bounds__(256) void k_wfrag(const _Float16* __restrict__ WT,
                                               _Float16* __restrict__ WF, int K){
    const int tid = threadIdx.x;
    const int l = tid & 63, f = tid >> 6;
    const int ct = blockIdx.y;
    const int kc = blockIdx.x*4 + f;
    const h8v v = *(const h8v*)(WT + (size_t)(ct*16 + (l & 15))*K + kc*32 + ((l >> 4) << 3));
    *(h8v*)(WF + ((size_t)(ct*(K >> 5) + kc)*64 + l)*8) = v;
}

__global__ __launch_bounds__(128) void k_proc_enc(const float* __restrict__ inputs,
                                                  const float* __restrict__ Wenc,
                                                  __half* __restrict__ pe_h){
    const int row = blockIdx.x;
    const int a   = threadIdx.x;
    const float* in = inputs + (size_t)row*EE;
    float acc = 0.f;
    for(int k=0;k<EE;k++) acc = fmaf(in[k], Wenc[k*AA + a], acc);
    pe_h[(size_t)row*AA + a] = __float2half(acc);
}

__global__ __launch_bounds__(320) void k_pip(const float* __restrict__ inputs,
                                             const float* __restrict__ Wp_c,
                                             __half* __restrict__ PIP){
    const int b = blockIdx.x >> 6, t4 = (blockIdx.x & 63)*4;
    __shared__ float xs[4*EE];
    const int tid = threadIdx.x;
    for(int i=tid; i<4*EE; i+=320) xs[i] = inputs[((size_t)b*TENC + t4)*EE + i];
    __syncthreads();
    const int tl = tid/80, m = tid%80;
    float acc = 0.f;
    for(int k=0;k<EE;k++) acc = fmaf(xs[tl*EE + k], Wp_c[k*NM + m], acc);
    PIP[((size_t)b*TENC + t4 + tl)*NM + m] = __float2half(acc);
}

// prenet for all t -> fp16 XS1h rows [t][b][0:256] (row stride K1)
__global__ __launch_bounds__(256) void k_prenet(const float* __restrict__ pmels,
                                                const float* __restrict__ pw1, const float* __restrict__ pb1,
                                                const float* __restrict__ pw2, const float* __restrict__ pb2,
                                                _Float16* __restrict__ XS1h){
    const int t = blockIdx.x;
    __shared__ float pm[BB*NM];
    __shared__ float h1s[BB*256];
    const int tid = threadIdx.x;
    for(int el=tid; el<BB*NM; el+=256){
        const int b = el/NM, m = el%NM;
        pm[el] = (t==0) ? 0.f : pmels[(size_t)(b*NM + m)*TDEC + (t-1)];
    }
    __syncthreads();
    const int a = tid;
    float acc[BB];
    #pragma unroll
    for(int b=0;b<BB;b++) acc[b]=0.f;
    for(int m=0;m<NM;m++){
        const float w = pw1[m*256 + a];
        #pragma unroll
        for(int b=0;b<BB;b++) acc[b] = fmaf(pm[b*NM+m], w, acc[b]);
    }
    {
        const float bias = pb1[a];
        for(int b=0;b<BB;b++) h1s[b*256+a] = fmaxf(acc[b]+bias, 0.f);
    }
    __syncthreads();
    #pragma unroll
    for(int b=0;b<BB;b++) acc[b]=0.f;
    for(int k=0;k<256;k++){
        const float w = pw2[k*256 + a];
        #pragma unroll
        for(int b=0;b<BB;b++) acc[b] = fmaf(h1s[b*256+k], w, acc[b]);
    }
    {
        const float bias = pb2[a];
        #pragma unroll
        for(int b=0;b<BB;b++)
            XS1h[((size_t)t*BB + b)*K1 + a] = (_Float16)fmaxf(acc[b]+bias, 0.f);
    }
}

__global__ void k_mloc(const float* __restrict__ conv_w, const float* __restrict__ conv_b,
                       const float* __restrict__ W_loc, float* __restrict__ Mloc, float* __restrict__ cbp){
    const int a = threadIdx.x;
    for(int d=0; d<31; d++){
        float s = 0.f;
        for(int ch=0; ch<32; ch++) s = fmaf(conv_w[ch*31 + d], W_loc[ch*AA + a], s);
        Mloc[d*AA + a] = s;
    }
    float s = 0.f;
    for(int ch=0; ch<32; ch++) s = fmaf(conv_b[ch], W_loc[ch*AA + a], s);
    cbp[a] = s;
}

// ---------------- persistent decode kernel ----------------

// Two-level grid barrier, relaxed-only atomics (no cache maintenance emitted).
// bb layout (uints): sub[g] at bb[g*32] (g<8), global cnt at bb[256], gen at bb[288].
__device__ __forceinline__ void gridbar(unsigned int* bb, unsigned int bi, int tid, int bid, int& dead){
    __syncthreads();
    if(tid == 0){
        const int g = bid & 7;
        unsigned int v = __hip_atomic_fetch_add(&bb[g*32], 1u, __ATOMIC_RELAXED, __HIP_MEMORY_SCOPE_AGENT);
        if(v == bi*32u - 1u){
            unsigned int w = __hip_atomic_fetch_add(&bb[256], 1u, __ATOMIC_RELAXED, __HIP_MEMORY_SCOPE_AGENT);
            if(w == bi*8u - 1u)
                __hip_atomic_store(&bb[288], bi, __ATOMIC_RELAXED, __HIP_MEMORY_SCOPE_AGENT);
        }
        if(!dead){
            unsigned int guard = 0;
            while(__hip_atomic_load(&bb[288], __ATOMIC_RELAXED, __HIP_MEMORY_SCOPE_AGENT) < bi){
                __builtin_amdgcn_s_sleep(2);
                if(++guard > 5000000u){ dead = 1; break; }   // deadlock failsafe: finish with garbage, don't hang
            }
        }
    }
    __syncthreads();
}

// LSTM phase: 256 blocks x 512 threads. 8 waves = 8 K-slices; each wave does both
// 16-row M-tiles with ONE B-fragment load. part: [8 kw][32 rows][pad 18].
// SC1: read A via agent-scope 8B atomic loads (XS2 parity buffers reuse addresses).
template<int K, bool SC1>
__device__ __forceinline__ void lstm_phase(
    const _Float16* __restrict__ XSh, const _Float16* __restrict__ WF,
    const float* __restrict__ bias, float& cv,
    _Float16* hA, int strideA, int offA,
    _Float16* hB, int strideB, int offB,
    float* part, float* stage, int tid, int bid)
{
    constexpr int KCN = K/256;
    const int l = tid & 63, kw = tid >> 6;
    f32x4 accL = {0.f,0.f,0.f,0.f}, accH = {0.f,0.f,0.f,0.f};
    const int r = l & 15;
    const _Float16* aptr = XSh + (size_t)r*K + (size_t)kw*KCN*32 + ((l >> 4) << 3);
    const _Float16* bptr = WF + ((size_t)(bid*(K >> 5) + kw*KCN)*64 + l)*8;
    #pragma unroll
    for(int kc=0; kc<KCN; kc++){
        const h8v b8 = *(const h8v*)(bptr + (size_t)kc*512);
        h8v aL, aH;
        if constexpr(SC1){
            union { unsigned long long u[2]; h8v v; } uL, uH;
            const unsigned long long* pL = (const unsigned long long*)(aptr + (size_t)kc*32);
            const unsigned long long* pH = (const unsigned long long*)(aptr + (size_t)16*K + (size_t)kc*32);
            uL.u[0] = ld64(pL);   uL.u[1] = ld64(pL+1);
            uH.u[0] = ld64(pH);   uH.u[1] = ld64(pH+1);
            aL = uL.v; aH = uH.v;
        } else {
            aL = *(const h8v*)(aptr + (size_t)kc*32);
            aH = *(const h8v*)(aptr + (size_t)16*K + (size_t)kc*32);
        }
        accL = __builtin_amdgcn_mfma_f32_16x16x32_f16(aL, b8, accL, 0, 0, 0);
        accH = __builtin_amdgcn_mfma_f32_16x16x32_f16(aH, b8, accH, 0, 0, 0);
    }
    // D layout: col = l&15, row(tile) = (l>>4)*4 + j
    {
        const int r0 = (l >> 4) << 2, c = l & 15;
        #pragma unroll
        for(int j=0;j<4;j++){
            part[(kw*32 + r0 + j)*18 + c]      = accL[j];
            part[(kw*32 + 16 + r0 + j)*18 + c] = accH[j];
        }
    }
    __syncthreads();
    if(tid < 128){
        const int b = tid & 31, cl = tid >> 5;
        float g[4];
        #pragma unroll
        for(int gi=0; gi<4; gi++){
            const int c2 = cl*4 + gi;
            float s = 0.f;
            #pragma unroll
            for(int q=0;q<8;q++) s += part[(q*32 + b)*18 + c2];
            const int p = bid*16 + c2;           // packed col = cell*4 + gate
            g[gi] = s + bias[(p & 3)*HH + (p >> 2)];
        }
        const float cn = sigf(g[1])*cv + sigf(g[0])*tanhfast(g[2]);
        cv = cn;
        stage[tid] = sigf(g[3])*tanhfast(cn);    // stage[cl*32+b]
    }
    __syncthreads();
    if(tid < 32){
        const int b = tid;
        unsigned long long pk =
              (unsigned long long)h2b(stage[0*32+b])
            | ((unsigned long long)h2b(stage[1*32+b]) << 16)
            | ((unsigned long long)h2b(stage[2*32+b]) << 32)
            | ((unsigned long long)h2b(stage[3*32+b]) << 48);
        st64((unsigned long long*)hA + ((size_t)b*strideA + offA + bid*4)/4, pk);
        if(hB) st64((unsigned long long*)hB + ((size_t)b*strideB + offB + bid*4)/4, pk);
    }
}

__global__ __launch_bounds__(512) void k_decode(
    _Float16* __restrict__ XS1h, _Float16* __restrict__ XS2h,
    const _Float16* __restrict__ W1F, const _Float16* __restrict__ W2F,
    const float* __restrict__ bl1, const float* __restrict__ bl2,
    const _Float16* __restrict__ WqT, const float* __restrict__ cbp,
    const float* __restrict__ Mloc, const float* __restrict__ ve,
    const __half* __restrict__ pe,
    const __half* __restrict__ inputs_h, const __half* __restrict__ PIP,
    const _Float16* __restrict__ WohT, const float* __restrict__ bp,
    float* __restrict__ out, unsigned int* __restrict__ bar)
{
    const int tid = threadIdx.x, bid = blockIdx.x;

    __shared__ float s_ml[31*AA];
    __shared__ float s_ves[AA];
    __shared__ float s_part[8*32*18];    // lstm partials; aliased: attn ep (1024) / ctxred (4096)
    __shared__ float s_h2s[1024];
    __shared__ float s_qc[4*AA];
    __shared__ float s_qf[AA];           // also lstm h-staging (128)
    __shared__ float s_awin[288];
    __shared__ float s_aw[TENC];
    __shared__ float s_awc[TENC];        // persistent per-b cumulative attention (blocks 0..31)
    __shared__ float s_red1[320];
    __shared__ float s_red2[320];
    __shared__ float s_sred[8];

    for(int i=tid; i<31*AA; i+=512) s_ml[i] = Mloc[i];
    if(tid < AA) s_ves[tid] = ve[tid];
    if(bid < BB) for(int i=tid; i<TENC; i+=512) s_awc[i] = 0.f;
    __syncthreads();

    float c1v = 0.f, c2v = 0.f;          // cell state in registers (tid<128 own 4 cells x 32 b)
    int dead = 0;
    unsigned int bi = 0;

    for(int t=0; t<TDEC; t++){
        const int p = t & 1;
        const _Float16* x1c = XS1h + (size_t)t*BB*K1;
        _Float16* x1n = XS1h + (size_t)(t+1)*BB*K1;
        _Float16* x2p = XS2h + (size_t)p*BB*K2;
        _Float16* x2n = XS2h + (size_t)(1-p)*BB*K2;

        // ---- phase 1: LSTM1 (A: per-t XS1h row, normal cached; fresh by cold-address) ----
        lstm_phase<K1,false>(x1c, W1F, bl1, c1v,
                             x2p, K2, 0,          // h1 -> XS2[p][b][0:1024]
                             x1n, K1, 768,        // h1 -> next XS1h row
                             s_part, s_qf, tid, bid);
        gridbar(bar, ++bi, tid, bid, dead);

        // ---- phase 2: LSTM2 (A: XS2 parity, address-reused -> sc1 loads) ----
        lstm_phase<K2,true>(x2p, W2F, bl2, c2v,
                            x2n, K2, 1024,        // h2 -> XS2[1-p][b][1024:2048]
                            (_Float16*)nullptr, 0, 0,
                            s_part, s_qf, tid, bid);
        gridbar(bar, ++bi, tid, bid, dead);

        // ---- phase 3: attention + output (blocks 0..31, one per b) ----
        if(bid < BB){
            const int b = bid;
            // h2 -> LDS (sc1: parity addresses)
            {
                const unsigned int* hp = (const unsigned int*)(x2n + (size_t)b*K2 + 1024);
                union { unsigned int u; _Float16 h[2]; } cu;
                cu.u = ld32(hp + tid);
                s_h2s[2*tid]   = (float)cu.h[0];
                s_h2s[2*tid+1] = (float)cu.h[1];
            }
            for(int i=tid; i<286; i+=512){
                const int g = i - 15;
                s_awin[i] = (g>=0 && g<TENC) ? s_awc[g] : 0.f;
            }
            __syncthreads();
            {   // q[a] = h2 . WqT[a][:], K split 4 ways
                const int a = tid & 127, tp = tid >> 7;
                float qa = 0.f;
                const _Float16* wq = WqT + (size_t)a*HH + tp*256;
                const float* hs = s_h2s + tp*256;
                for(int kb=0; kb<256; kb+=8){
                    const h8v w8 = __builtin_nontemporal_load((const h8v*)(wq + kb));
                    #pragma unroll
                    for(int i2=0;i2<8;i2++) qa = fmaf((float)w8[i2], hs[kb+i2], qa);
                }
                s_qc[tp*AA + a] = qa;
            }
            __syncthreads();
            if(tid < AA) s_qf[tid] = s_qc[tid] + s_qc[AA+tid] + s_qc[2*AA+tid] + s_qc[3*AA+tid] + cbp[tid];
            __syncthreads();
            // energies: (ti = t-index, ah = 32-wide a-block), 2 outer iters cover ah 0..3
            float* s_ep = s_part;
            #pragma unroll
            for(int it=0; it<2; it++){
                const int ti = tid & 255, ah = (tid >> 8) + 2*it;
                const int a0 = ah*32;
                float s[32];
                const h8v* pp = (const h8v*)((const _Float16*)pe + ((size_t)(b*TENC + ti))*AA + a0);
                #pragma unroll
                for(int vq=0; vq<4; vq++){
                    const h8v pv = __builtin_nontemporal_load(pp + vq);
                    #pragma unroll
                    for(int j=0;j<8;j++) s[vq*8+j] = s_qf[a0+vq*8+j] + (float)pv[j];
                }
                for(int d=0; d<31; d++){
                    const float w = s_awin[ti+d];
                    #pragma unroll
                    for(int j=0;j<32;j++) s[j] = fmaf(w, s_ml[d*AA + a0 + j], s[j]);
                }
                float es = 0.f;
                #pragma unroll
                for(int j=0;j<32;j++) es = fmaf(tanhfast(s[j]), s_ves[a0+j], es);
                s_ep[ah*256 + ti] = es;
            }
            __syncthreads();
            // softmax over 256 energies
            float e = -1e30f;
            if(tid < 256) e = s_ep[tid] + s_ep[256+tid] + s_ep[512+tid] + s_ep[768+tid];
            float m_ = e;
            #pragma unroll
            for(int o=32;o>=1;o>>=1) m_ = fmaxf(m_, __shfl_xor(m_, o));
            if((tid&63)==0 && tid<256) s_sred[tid>>6] = m_;
            __syncthreads();
            const float mm = fmaxf(fmaxf(s_sred[0],s_sred[1]), fmaxf(s_sred[2],s_sred[3]));
            const float pv2 = (tid<256) ? __expf(e - mm) : 0.f;
            float sum = pv2;
            #pragma unroll
            for(int o=32;o>=1;o>>=1) sum += __shfl_xor(sum, o);
            if((tid&63)==0 && tid<256) s_sred[4+(tid>>6)] = sum;
            __syncthreads();
            sum = s_sred[4]+s_sred[5]+s_sred[6]+s_sred[7];
            if(tid < 256){
                const float awv = pv2/sum;
                s_aw[tid] = awv;
                s_awc[tid] += awv;
            }
            __syncthreads();
            // ctx: (ch8 = 8 channels, tq = t-slice of 8) + LDS reduce
            float* ctxred = s_part;
            {
                const int ch8 = tid & 63, tq = tid >> 6;
                const _Float16* ib = (const _Float16*)inputs_h + (size_t)b*TENC*EE + ch8*8;
                float a_[8];
                #pragma unroll
                for(int j=0;j<8;j++) a_[j]=0.f;
                for(int tt=tq; tt<TENC; tt+=8){
                    const float wv = s_aw[tt];
                    const h8v x8 = __builtin_nontemporal_load((const h8v*)(ib + (size_t)tt*EE));
                    #pragma unroll
                    for(int j=0;j<8;j++) a_[j] = fmaf(wv, (float)x8[j], a_[j]);
                }
                #pragma unroll
                for(int j=0;j<8;j++) ctxred[tq*512 + ch8*8 + j] = a_[j];
            }
            __syncthreads();
            if(tid < 256){   // ctx -> next XS1h row (paired sc1 4B stores)
                const int ch = 2*tid;
                float s0=0.f, s1=0.f;
                #pragma unroll
                for(int q=0;q<8;q++){ s0 += ctxred[q*512 + ch]; s1 += ctxred[q*512 + ch + 1]; }
                union { unsigned int u; _Float16 h[2]; } cu;
                cu.h[0] = (_Float16)s0; cu.h[1] = (_Float16)s1;
                st32((unsigned int*)(x1n + (size_t)b*K1 + 256) + tid, cu.u);
            }
            if(tid < 320){   // output projection: s1 = h2 @ WohT, s2 = aw . PIP (K quarters)
                const int m2 = tid % 80, kh = tid / 80;
                float s1 = 0.f;
                const _Float16* wo = WohT + (size_t)m2*HH + kh*256;
                const float* hs = s_h2s + kh*256;
                for(int kb=0; kb<256; kb+=8){
                    const h8v w8 = __builtin_nontemporal_load((const h8v*)(wo + kb));
                    #pragma unroll
                    for(int i2=0;i2<8;i2++) s1 = fmaf((float)w8[i2], hs[kb+i2], s1);
                }
                s_red1[kh*80 + m2] = s1;
                float s2 = 0.f;
                const unsigned short* pp2 = (const unsigned short*)PIP + ((size_t)(b*TENC) + kh*64)*NM + m2;
                const float* awp = s_aw + kh*64;
                for(int tt=0; tt<64; tt++){
                    const unsigned short us = __builtin_nontemporal_load(pp2 + (size_t)tt*NM);
                    s2 = fmaf(awp[tt], b2f(us), s2);
                }
                s_red2[kh*80 + m2] = s2;
            }
            __syncthreads();
            if(tid < NM){
                const float o = s_red1[tid]+s_red1[80+tid]+s_red1[160+tid]+s_red1[240+tid]
                              + s_red2[tid]+s_red2[80+tid]+s_red2[160+tid]+s_red2[240+tid] + bp[tid];
                out[((size_t)t*BB + b)*NM + tid] = o;
            }
        }
        gridbar(bar, ++bi, tid, bid, dead);
    }
}

// ---------------- host ----------------

extern "C" void kernel_launch(void* const* d_in, const int* in_sizes, int n_in,
                              void* d_out, int out_size, void* d_ws, size_t ws_size,
                              hipStream_t stream)
{
    const float* inputs = (const float*)d_in[0];
    const float* pmels  = (const float*)d_in[1];
    const float* W_enc  = (const float*)d_in[2];
    const float* W_q    = (const float*)d_in[3];
    const float* conv_w = (const float*)d_in[4];
    const float* conv_b = (const float*)d_in[5];
    const float* W_loc  = (const float*)d_in[6];
    const float* v_e    = (const float*)d_in[7];
    const float* pw1    = (const float*)d_in[8];
    const float* pb1    = (const float*)d_in[9];
    const float* pw2    = (const float*)d_in[10];
    const float* pb2    = (const float*)d_in[11];
    const float* Wi1    = (const float*)d_in[12];
    const float* Wh1    = (const float*)d_in[13];
    const float* bl1    = (const float*)d_in[14];
    const float* Wi2    = (const float*)d_in[15];
    const float* Wh2    = (const float*)d_in[16];
    const float* bl2    = (const float*)d_in[17];
    const float* Wp     = (const float*)d_in[18];
    const float* bp     = (const float*)d_in[19];
    float* out = (float*)d_out;
    (void)in_sizes; (void)n_in; (void)out_size; (void)ws_size;

    char* ws = (char*)d_ws;
    size_t off = 0;
    auto carve = [&](size_t bytes)->char* {
        char* p = ws + off;
        off += (bytes + 255) & ~(size_t)255;
        return p;
    };
    __half*    inputs_h = (__half*)   carve((size_t)BB*TENC*EE*2);
    __half*    pe_h     = (__half*)   carve((size_t)BB*TENC*AA*2);
    __half*    PIP      = (__half*)   carve((size_t)BB*TENC*NM*2);
    _Float16*  XS1h     = (_Float16*) carve((size_t)(TDEC+1)*BB*K1*2);
    _Float16*  XS2h     = (_Float16*) carve((size_t)2*BB*K2*2);
    _Float16*  WA       = (_Float16*) carve((size_t)GG*K2*2);   // W2T scratch, later reused as W1F
    _Float16*  WB       = (_Float16*) carve((size_t)GG*K1*2);   // W1T scratch
    _Float16*  W2F      = (_Float16*) carve((size_t)GG*K2*2);
    _Float16*  WqT      = (_Float16*) carve((size_t)AA*HH*2);
    _Float16*  WohT     = (_Float16*) carve((size_t)NM*HH*2);
    unsigned int* bar   = (unsigned int*)carve(320*4);
    float* Mloc = (float*)carve((size_t)31*AA*4);
    float* cbp  = (float*)carve((size_t)AA*4);
    _Float16* W1F = WA;   // alias: W2T dead once W2F is built

    // ---- one-time precompute (per launch) ----
    k_zero<<<1,320,0,stream>>>((float*)bar, 320);                             // barrier counters
    k_zero<<<(2*BB*K2/2+255)/256,256,0,stream>>>((float*)XS2h, 2*BB*K2/2);    // h1,h2 parity = 0
    k_zero<<<(BB*K1/2+255)/256,256,0,stream>>>((float*)XS1h, BB*K1/2);        // row t=0
    k_cvt_half<<<2048,256,0,stream>>>(inputs, inputs_h, BB*TENC*EE);
    k_proc_enc<<<BB*TENC,128,0,stream>>>(inputs, W_enc, pe_h);
    k_prenet<<<TDEC,256,0,stream>>>(pmels, pw1,pb1,pw2,pb2, XS1h);
    k_mloc<<<1,128,0,stream>>>(conv_w, conv_b, W_loc, Mloc, cbp);
    k_transpose2<<<dim3(GG/32, 1024/32),256,0,stream>>>(Wi2, WA, 1024, GG, K2, 0,    1);
    k_transpose2<<<dim3(GG/32, 1024/32),256,0,stream>>>(Wh2, WA, 1024, GG, K2, 1024, 1);
    k_wfrag<<<dim3(K2/128, GG/16),256,0,stream>>>(WA, W2F, K2);
    k_transpose2<<<dim3(GG/32,  768/32),256,0,stream>>>(Wi1, WB, 768,  GG, K1, 0,    1);
    k_transpose2<<<dim3(GG/32, 1024/32),256,0,stream>>>(Wh1, WB, 1024, GG, K1, 768,  1);
    k_wfrag<<<dim3(K1/128, GG/16),256,0,stream>>>(WB, W1F, K1);
    k_transpose2<<<dim3(AA/32, 1024/32),256,0,stream>>>(W_q, WqT, 1024, AA, HH, 0,   0);
    k_transpose2<<<dim3(3,     1024/32),256,0,stream>>>(Wp,  WohT, 1024, NM, HH, 0,  0);
    k_pip<<<BB*64,320,0,stream>>>(inputs, Wp + (size_t)HH*NM, PIP);

    // ---- persistent decode: ONE cooperative kernel, custom relaxed barrier ----
    {
        void* ka[17];
        ka[0]  = (void*)&XS1h;
        ka[1]  = (void*)&XS2h;
        ka[2]  = (void*)&W1F;
        ka[3]  = (void*)&W2F;
        ka[4]  = (void*)&bl1;
        ka[5]  = (void*)&bl2;
        ka[6]  = (void*)&WqT;
        ka[7]  = (void*)&cbp;
        ka[8]  = (void*)&Mloc;
        ka[9]  = (void*)&v_e;
        ka[10] = (void*)&pe_h;
        ka[11] = (void*)&inputs_h;
        ka[12] = (void*)&PIP;
        ka[13] = (void*)&WohT;
        ka[14] = (void*)&bp;
        ka[15] = (void*)&out;
        ka[16] = (void*)&bar;
        hipLaunchCooperativeKernel((const void*)k_decode, dim3(256), dim3(512),
                                   ka, 0, stream);
    }
}

// Round 5
// 11973.897 us; speedup vs baseline: 3.6629x; 1.6009x over previous
//
#include <hip/hip_runtime.h>
#include <hip/hip_fp16.h>

#define BB   32
#define TENC 256
#define EE   512
#define TDEC 200
#define NM   80
#define HH   1024
#define AA   128
#define GG   4096
#define K1   1792   // x(256)|ctx(512)|h1(1024)
#define K2   2048   // h1|h2

#define NGRP  16
#define GRPSZ 16    // 256 blocks / 16 groups

typedef _Float16 h8v  __attribute__((ext_vector_type(8)));
typedef float    f32x4 __attribute__((ext_vector_type(4)));

__device__ __forceinline__ float sigf(float x){ return 1.0f/(1.0f + __expf(-x)); }
__device__ __forceinline__ float tanhfast(float x){ return 1.0f - 2.0f/(1.0f + __expf(2.0f*x)); }

__device__ __forceinline__ unsigned short h2b(float f){
    _Float16 h = (_Float16)f; unsigned short u; __builtin_memcpy(&u, &h, 2); return u;
}
__device__ __forceinline__ void st64(unsigned long long* p, unsigned long long v){
    __hip_atomic_store(p, v, __ATOMIC_RELAXED, __HIP_MEMORY_SCOPE_AGENT);
}
__device__ __forceinline__ void st32(unsigned int* p, unsigned int v){
    __hip_atomic_store(p, v, __ATOMIC_RELAXED, __HIP_MEMORY_SCOPE_AGENT);
}
__device__ __forceinline__ unsigned long long ld64(const unsigned long long* p){
    return __hip_atomic_load(p, __ATOMIC_RELAXED, __HIP_MEMORY_SCOPE_AGENT);
}
__device__ __forceinline__ unsigned int ld32(const unsigned int* p){
    return __hip_atomic_load(p, __ATOMIC_RELAXED, __HIP_MEMORY_SCOPE_AGENT);
}

// ---------------- precompute kernels ----------------

__global__ void k_zero(float* __restrict__ p, int n){
    int i = blockIdx.x*blockDim.x + threadIdx.x;
    if(i < n) p[i] = 0.f;
}

__global__ void k_cvt_half(const float* __restrict__ src, __half* __restrict__ dst, int n){
    int i = blockIdx.x*blockDim.x + threadIdx.x;
    int stride = gridDim.x*blockDim.x;
    for(; i<n; i+=stride) dst[i] = __float2half(src[i]);
}

// transpose fp32 src[k][c] -> fp16 dst[p][kOff+k]; pack=1 remaps c (gate*1024+cell) -> p=cell*4+gate
__global__ __launch_bounds__(256) void k_transpose2(const float* __restrict__ src,
                                                    _Float16* __restrict__ dst,
                                                    int K, int C, int dstStride, int kOff, int pack){
    __shared__ float tile[32][33];
    const int tid = threadIdx.x;
    const int c0 = blockIdx.x*32, k0 = blockIdx.y*32;
    const int cl = tid & 31, r8 = tid >> 5;
    #pragma unroll
    for(int i=0;i<4;i++){
        const int k = k0 + r8 + i*8;
        if(k < K && c0+cl < C) tile[r8 + i*8][cl] = src[(size_t)k*C + c0 + cl];
    }
    __syncthreads();
    const int kl = tid & 31, c8 = tid >> 5;
    #pragma unroll
    for(int i=0;i<4;i++){
        const int c = c0 + c8 + i*8;
        if(c < C && k0+kl < K){
            const int p = pack ? ((c & 1023)*4 + (c >> 10)) : c;
            dst[(size_t)p*dstStride + kOff + k0 + kl] = (_Float16)tile[kl][c8 + i*8];
        }
    }
}

// Rearrange WT fp16 [P=4096][K] into MFMA B-fragment order.
__global__ __launch_bounds__(256) void k_wfrag(const _Float16* __restrict__ WT,
                                               _Float16* __restrict__ WF, int K){
    const int tid = threadIdx.x;
    const int l = tid & 63, f = tid >> 6;
    const int ct = blockIdx.y;
    const int kc = blockIdx.x*4 + f;
    const h8v v = *(const h8v*)(WT + (size_t)(ct*16 + (l & 15))*K + kc*32 + ((l >> 4) << 3));
    *(h8v*)(WF + ((size_t)(ct*(K >> 5) + kc)*64 + l)*8) = v;
}

__global__ __launch_bounds__(128) void k_proc_enc(const float* __restrict__ inputs,
                                                  const float* __restrict__ Wenc,
                                                  __half* __restrict__ pe_h){
    const int row = blockIdx.x;
    const int a   = threadIdx.x;
    const float* in = inputs + (size_t)row*EE;
    float acc = 0.f;
    for(int k=0;k<EE;k++) acc = fmaf(in[k], Wenc[k*AA + a], acc);
    pe_h[(size_t)row*AA + a] = __float2half(acc);
}

__global__ __launch_bounds__(320) void k_pip(const float* __restrict__ inputs,
                                             const float* __restrict__ Wp_c,
                                             __half* __restrict__ PIP){
    const int b = blockIdx.x >> 6, t4 = (blockIdx.x & 63)*4;
    __shared__ float xs[4*EE];
    const int tid = threadIdx.x;
    for(int i=tid; i<4*EE; i+=320) xs[i] = inputs[((size_t)b*TENC + t4)*EE + i];
    __syncthreads();
    const int tl = tid/80, m = tid%80;
    float acc = 0.f;
    for(int k=0;k<EE;k++) acc = fmaf(xs[tl*EE + k], Wp_c[k*NM + m], acc);
    PIP[((size_t)b*TENC + t4 + tl)*NM + m] = __float2half(acc);
}

// prenet for all t -> fp16 XS1h rows [t][b][0:256] (row stride K1)
__global__ __launch_bounds__(256) void k_prenet(const float* __restrict__ pmels,
                                                const float* __restrict__ pw1, const float* __restrict__ pb1,
                                                const float* __restrict__ pw2, const float* __restrict__ pb2,
                                                _Float16* __restrict__ XS1h){
    const int t = blockIdx.x;
    __shared__ float pm[BB*NM];
    __shared__ float h1s[BB*256];
    const int tid = threadIdx.x;
    for(int el=tid; el<BB*NM; el+=256){
        const int b = el/NM, m = el%NM;
        pm[el] = (t==0) ? 0.f : pmels[(size_t)(b*NM + m)*TDEC + (t-1)];
    }
    __syncthreads();
    const int a = tid;
    float acc[BB];
    #pragma unroll
    for(int b=0;b<BB;b++) acc[b]=0.f;
    for(int m=0;m<NM;m++){
        const float w = pw1[m*256 + a];
        #pragma unroll
        for(int b=0;b<BB;b++) acc[b] = fmaf(pm[b*NM+m], w, acc[b]);
    }
    {
        const float bias = pb1[a];
        for(int b=0;b<BB;b++) h1s[b*256+a] = fmaxf(acc[b]+bias, 0.f);
    }
    __syncthreads();
    #pragma unroll
    for(int b=0;b<BB;b++) acc[b]=0.f;
    for(int k=0;k<256;k++){
        const float w = pw2[k*256 + a];
        #pragma unroll
        for(int b=0;b<BB;b++) acc[b] = fmaf(h1s[b*256+k], w, acc[b]);
    }
    {
        const float bias = pb2[a];
        #pragma unroll
        for(int b=0;b<BB;b++)
            XS1h[((size_t)t*BB + b)*K1 + a] = (_Float16)fmaxf(acc[b]+bias, 0.f);
    }
}

__global__ void k_mloc(const float* __restrict__ conv_w, const float* __restrict__ conv_b,
                       const float* __restrict__ W_loc, float* __restrict__ Mloc, float* __restrict__ cbp){
    const int a = threadIdx.x;
    for(int d=0; d<31; d++){
        float s = 0.f;
        for(int ch=0; ch<32; ch++) s = fmaf(conv_w[ch*31 + d], W_loc[ch*AA + a], s);
        Mloc[d*AA + a] = s;
    }
    float s = 0.f;
    for(int ch=0; ch<32; ch++) s = fmaf(conv_b[ch], W_loc[ch*AA + a], s);
    cbp[a] = s;
}

// ---------------- persistent decode kernel ----------------

// Mailbox grid barrier, relaxed-only atomics (no cache maintenance emitted).
// bar layout (uints, 32-uint cache lines):
//   sub-counter g  : bar[g*32]            (g = 0..15, 16 blocks each)
//   master counter : bar[512]
//   master gen     : bar[544]
//   mailbox[bid]   : bar[576 + bid*32]
// Release: 16 relay blocks (bid%16==0) poll master gen, then write their 15
// members' private mailbox lines -> no polling contention on any shared line.
__device__ __forceinline__ void gridbar(unsigned int* bb, unsigned int bi, int tid, int bid, int& dead){
    __syncthreads();
    if(tid == 0){
        const int g = bid >> 4;
        unsigned int v = __hip_atomic_fetch_add(&bb[g*32], 1u, __ATOMIC_RELAXED, __HIP_MEMORY_SCOPE_AGENT);
        if(v == bi*GRPSZ - 1u){
            unsigned int w = __hip_atomic_fetch_add(&bb[512], 1u, __ATOMIC_RELAXED, __HIP_MEMORY_SCOPE_AGENT);
            if(w == bi*NGRP - 1u)
                st32(&bb[544], bi);
        }
        if(!dead){
            unsigned int guard = 0;
            if((bid & 15) == 0){
                while(ld32(&bb[544]) < bi){
                    __builtin_amdgcn_s_sleep(4);
                    if(++guard > 3000000u){ dead = 1; break; }   // failsafe: no hang
                }
                #pragma unroll
                for(int m=1; m<GRPSZ; m++) st32(&bb[576 + (bid+m)*32], bi);
            } else {
                while(ld32(&bb[576 + bid*32]) < bi){
                    __builtin_amdgcn_s_sleep(4);
                    if(++guard > 3000000u){ dead = 1; break; }
                }
            }
        }
    }
    __syncthreads();
}

// LSTM phase: 256 blocks x 512 threads. 8 waves = 8 K-slices; each wave does both
// 16-row M-tiles with ONE B-fragment load. part: [8 kw][32 rows][pad 18].
// SC1: read A via agent-scope 8B atomic loads (XS2 parity buffers reuse addresses).
template<int K, bool SC1>
__device__ __forceinline__ void lstm_phase(
    const _Float16* __restrict__ XSh, const _Float16* __restrict__ WF,
    const float* __restrict__ bias, float& cv,
    _Float16* hA, int strideA, int offA,
    _Float16* hB, int strideB, int offB,
    float* part, float* stage, int tid, int bid)
{
    constexpr int KCN = K/256;
    const int l = tid & 63, kw = tid >> 6;
    f32x4 accL = {0.f,0.f,0.f,0.f}, accH = {0.f,0.f,0.f,0.f};
    const int r = l & 15;
    const _Float16* aptr = XSh + (size_t)r*K + (size_t)kw*KCN*32 + ((l >> 4) << 3);
    const _Float16* bptr = WF + ((size_t)(bid*(K >> 5) + kw*KCN)*64 + l)*8;
    #pragma unroll
    for(int kc=0; kc<KCN; kc++){
        const h8v b8 = *(const h8v*)(bptr + (size_t)kc*512);
        h8v aL, aH;
        if constexpr(SC1){
            union { unsigned long long u[2]; h8v v; } uL, uH;
            const unsigned long long* pL = (const unsigned long long*)(aptr + (size_t)kc*32);
            const unsigned long long* pH = (const unsigned long long*)(aptr + (size_t)16*K + (size_t)kc*32);
            uL.u[0] = ld64(pL);   uL.u[1] = ld64(pL+1);
            uH.u[0] = ld64(pH);   uH.u[1] = ld64(pH+1);
            aL = uL.v; aH = uH.v;
        } else {
            aL = *(const h8v*)(aptr + (size_t)kc*32);
            aH = *(const h8v*)(aptr + (size_t)16*K + (size_t)kc*32);
        }
        accL = __builtin_amdgcn_mfma_f32_16x16x32_f16(aL, b8, accL, 0, 0, 0);
        accH = __builtin_amdgcn_mfma_f32_16x16x32_f16(aH, b8, accH, 0, 0, 0);
    }
    // D layout: col = l&15, row(tile) = (l>>4)*4 + j
    {
        const int r0 = (l >> 4) << 2, c = l & 15;
        #pragma unroll
        for(int j=0;j<4;j++){
            part[(kw*32 + r0 + j)*18 + c]      = accL[j];
            part[(kw*32 + 16 + r0 + j)*18 + c] = accH[j];
        }
    }
    __syncthreads();
    if(tid < 128){
        const int b = tid & 31, cl = tid >> 5;
        float g[4];
        #pragma unroll
        for(int gi=0; gi<4; gi++){
            const int c2 = cl*4 + gi;
            float s = 0.f;
            #pragma unroll
            for(int q=0;q<8;q++) s += part[(q*32 + b)*18 + c2];
            const int p = bid*16 + c2;           // packed col = cell*4 + gate
            g[gi] = s + bias[(p & 3)*HH + (p >> 2)];
        }
        const float cn = sigf(g[1])*cv + sigf(g[0])*tanhfast(g[2]);
        cv = cn;
        stage[tid] = sigf(g[3])*tanhfast(cn);    // stage[cl*32+b]
    }
    __syncthreads();
    if(tid < 32){
        const int b = tid;
        unsigned long long pk =
              (unsigned long long)h2b(stage[0*32+b])
            | ((unsigned long long)h2b(stage[1*32+b]) << 16)
            | ((unsigned long long)h2b(stage[2*32+b]) << 32)
            | ((unsigned long long)h2b(stage[3*32+b]) << 48);
        st64((unsigned long long*)hA + ((size_t)b*strideA + offA + bid*4)/4, pk);
        if(hB) st64((unsigned long long*)hB + ((size_t)b*strideB + offB + bid*4)/4, pk);
    }
}

__global__ __launch_bounds__(512) void k_decode(
    _Float16* __restrict__ XS1h, _Float16* __restrict__ XS2h,
    const _Float16* __restrict__ W1F, const _Float16* __restrict__ W2F,
    const float* __restrict__ bl1, const float* __restrict__ bl2,
    const _Float16* __restrict__ WqT, const float* __restrict__ cbp,
    const float* __restrict__ Mloc, const float* __restrict__ ve,
    const __half* __restrict__ pe,
    const __half* __restrict__ inputs_h, const __half* __restrict__ PIP,
    const _Float16* __restrict__ WohT, const float* __restrict__ bp,
    float* __restrict__ out, unsigned int* __restrict__ bar)
{
    const int tid = threadIdx.x, bid = blockIdx.x;

    __shared__ float s_ml[31*AA];
    __shared__ float s_ves[AA];
    __shared__ float s_part[8*32*18];    // lstm partials; aliased: attn ep (1024) / ctxred (4096)
    __shared__ float s_h2s[1024];
    __shared__ float s_qc[4*AA];
    __shared__ float s_qf[AA];           // also lstm h-staging (128)
    __shared__ float s_awin[288];
    __shared__ float s_aw[TENC];
    __shared__ float s_awc[TENC];        // persistent per-b cumulative attention (blocks 0..31)
    __shared__ float s_red1[320];
    __shared__ float s_red2[320];
    __shared__ float s_sred[8];

    for(int i=tid; i<31*AA; i+=512) s_ml[i] = Mloc[i];
    if(tid < AA) s_ves[tid] = ve[tid];
    if(bid < BB) for(int i=tid; i<TENC; i+=512) s_awc[i] = 0.f;
    __syncthreads();

    float c1v = 0.f, c2v = 0.f;          // cell state in registers (tid<128 own 4 cells x 32 b)
    int dead = 0;
    unsigned int bi = 0;

    for(int t=0; t<TDEC; t++){
        const int p = t & 1;
        const _Float16* x1c = XS1h + (size_t)t*BB*K1;
        _Float16* x1n = XS1h + (size_t)(t+1)*BB*K1;
        _Float16* x2p = XS2h + (size_t)p*BB*K2;
        _Float16* x2n = XS2h + (size_t)(1-p)*BB*K2;

        // ---- phase 1: LSTM1 (A: per-t XS1h row, normal cached; fresh by cold-address) ----
        lstm_phase<K1,false>(x1c, W1F, bl1, c1v,
                             x2p, K2, 0,          // h1 -> XS2[p][b][0:1024]
                             x1n, K1, 768,        // h1 -> next XS1h row
                             s_part, s_qf, tid, bid);
        gridbar(bar, ++bi, tid, bid, dead);

        // ---- phase 2: LSTM2 (A: XS2 parity, address-reused -> sc1 loads) ----
        lstm_phase<K2,true>(x2p, W2F, bl2, c2v,
                            x2n, K2, 1024,        // h2 -> XS2[1-p][b][1024:2048]
                            (_Float16*)nullptr, 0, 0,
                            s_part, s_qf, tid, bid);
        gridbar(bar, ++bi, tid, bid, dead);

        // ---- phase 3: attention + output (blocks 0..31, one per b) ----
        if(bid < BB){
            const int b = bid;
            // h2 -> LDS (sc1: parity addresses)
            {
                const unsigned int* hp = (const unsigned int*)(x2n + (size_t)b*K2 + 1024);
                union { unsigned int u; _Float16 h[2]; } cu;
                cu.u = ld32(hp + tid);
                s_h2s[2*tid]   = (float)cu.h[0];
                s_h2s[2*tid+1] = (float)cu.h[1];
            }
            for(int i=tid; i<286; i+=512){
                const int g = i - 15;
                s_awin[i] = (g>=0 && g<TENC) ? s_awc[g] : 0.f;
            }
            __syncthreads();
            {   // q[a] = h2 . WqT[a][:], K split 4 ways
                const int a = tid & 127, tp = tid >> 7;
                float qa = 0.f;
                const _Float16* wq = WqT + (size_t)a*HH + tp*256;
                const float* hs = s_h2s + tp*256;
                for(int kb=0; kb<256; kb+=8){
                    const h8v w8 = *(const h8v*)(wq + kb);
                    #pragma unroll
                    for(int i2=0;i2<8;i2++) qa = fmaf((float)w8[i2], hs[kb+i2], qa);
                }
                s_qc[tp*AA + a] = qa;
            }
            __syncthreads();
            if(tid < AA) s_qf[tid] = s_qc[tid] + s_qc[AA+tid] + s_qc[2*AA+tid] + s_qc[3*AA+tid] + cbp[tid];
            __syncthreads();
            // energies: (ti = t-index, ah = 32-wide a-block), 2 outer iters cover ah 0..3
            float* s_ep = s_part;
            #pragma unroll
            for(int it=0; it<2; it++){
                const int ti = tid & 255, ah = (tid >> 8) + 2*it;
                const int a0 = ah*32;
                float s[32];
                const h8v* pp = (const h8v*)((const _Float16*)pe + ((size_t)(b*TENC + ti))*AA + a0);
                #pragma unroll
                for(int vq=0; vq<4; vq++){
                    const h8v pv = pp[vq];
                    #pragma unroll
                    for(int j=0;j<8;j++) s[vq*8+j] = s_qf[a0+vq*8+j] + (float)pv[j];
                }
                for(int d=0; d<31; d++){
                    const float w = s_awin[ti+d];
                    #pragma unroll
                    for(int j=0;j<32;j++) s[j] = fmaf(w, s_ml[d*AA + a0 + j], s[j]);
                }
                float es = 0.f;
                #pragma unroll
                for(int j=0;j<32;j++) es = fmaf(tanhfast(s[j]), s_ves[a0+j], es);
                s_ep[ah*256 + ti] = es;
            }
            __syncthreads();
            // softmax over 256 energies
            float e = -1e30f;
            if(tid < 256) e = s_ep[tid] + s_ep[256+tid] + s_ep[512+tid] + s_ep[768+tid];
            float m_ = e;
            #pragma unroll
            for(int o=32;o>=1;o>>=1) m_ = fmaxf(m_, __shfl_xor(m_, o));
            if((tid&63)==0 && tid<256) s_sred[tid>>6] = m_;
            __syncthreads();
            const float mm = fmaxf(fmaxf(s_sred[0],s_sred[1]), fmaxf(s_sred[2],s_sred[3]));
            const float pv2 = (tid<256) ? __expf(e - mm) : 0.f;
            float sum = pv2;
            #pragma unroll
            for(int o=32;o>=1;o>>=1) sum += __shfl_xor(sum, o);
            if((tid&63)==0 && tid<256) s_sred[4+(tid>>6)] = sum;
            __syncthreads();
            sum = s_sred[4]+s_sred[5]+s_sred[6]+s_sred[7];
            if(tid < 256){
                const float awv = pv2/sum;
                s_aw[tid] = awv;
                s_awc[tid] += awv;
            }
            __syncthreads();
            // ctx: (ch8 = 8 channels, tq = t-slice of 8) + LDS reduce
            float* ctxred = s_part;
            {
                const int ch8 = tid & 63, tq = tid >> 6;
                const _Float16* ib = (const _Float16*)inputs_h + (size_t)b*TENC*EE + ch8*8;
                float a_[8];
                #pragma unroll
                for(int j=0;j<8;j++) a_[j]=0.f;
                for(int tt=tq; tt<TENC; tt+=8){
                    const float wv = s_aw[tt];
                    const h8v x8 = *(const h8v*)(ib + (size_t)tt*EE);
                    #pragma unroll
                    for(int j=0;j<8;j++) a_[j] = fmaf(wv, (float)x8[j], a_[j]);
                }
                #pragma unroll
                for(int j=0;j<8;j++) ctxred[tq*512 + ch8*8 + j] = a_[j];
            }
            __syncthreads();
            if(tid < 256){   // ctx -> next XS1h row (paired sc1 4B stores)
                const int ch = 2*tid;
                float s0=0.f, s1=0.f;
                #pragma unroll
                for(int q=0;q<8;q++){ s0 += ctxred[q*512 + ch]; s1 += ctxred[q*512 + ch + 1]; }
                union { unsigned int u; _Float16 h[2]; } cu;
                cu.h[0] = (_Float16)s0; cu.h[1] = (_Float16)s1;
                st32((unsigned int*)(x1n + (size_t)b*K1 + 256) + tid, cu.u);
            }
            if(tid < 320){   // output projection: s1 = h2 @ WohT, s2 = aw . PIP (K quarters)
                const int m2 = tid % 80, kh = tid / 80;
                float s1 = 0.f;
                const _Float16* wo = WohT + (size_t)m2*HH + kh*256;
                const float* hs = s_h2s + kh*256;
                for(int kb=0; kb<256; kb+=8){
                    const h8v w8 = *(const h8v*)(wo + kb);
                    #pragma unroll
                    for(int i2=0;i2<8;i2++) s1 = fmaf((float)w8[i2], hs[kb+i2], s1);
                }
                s_red1[kh*80 + m2] = s1;
                float s2 = 0.f;
                const __half* pp2 = PIP + ((size_t)(b*TENC) + kh*64)*NM + m2;
                const float* awp = s_aw + kh*64;
                for(int tt=0; tt<64; tt++)
                    s2 = fmaf(awp[tt], __half2float(pp2[(size_t)tt*NM]), s2);
                s_red2[kh*80 + m2] = s2;
            }
            __syncthreads();
            if(tid < NM){
                const float o = s_red1[tid]+s_red1[80+tid]+s_red1[160+tid]+s_red1[240+tid]
                              + s_red2[tid]+s_red2[80+tid]+s_red2[160+tid]+s_red2[240+tid] + bp[tid];
                out[((size_t)t*BB + b)*NM + tid] = o;
            }
        }
        gridbar(bar, ++bi, tid, bid, dead);
    }
}

// ---------------- host ----------------

extern "C" void kernel_launch(void* const* d_in, const int* in_sizes, int n_in,
                              void* d_out, int out_size, void* d_ws, size_t ws_size,
                              hipStream_t stream)
{
    const float* inputs = (const float*)d_in[0];
    const float* pmels  = (const float*)d_in[1];
    const float* W_enc  = (const float*)d_in[2];
    const float* W_q    = (const float*)d_in[3];
    const float* conv_w = (const float*)d_in[4];
    const float* conv_b = (const float*)d_in[5];
    const float* W_loc  = (const float*)d_in[6];
    const float* v_e    = (const float*)d_in[7];
    const float* pw1    = (const float*)d_in[8];
    const float* pb1    = (const float*)d_in[9];
    const float* pw2    = (const float*)d_in[10];
    const float* pb2    = (const float*)d_in[11];
    const float* Wi1    = (const float*)d_in[12];
    const float* Wh1    = (const float*)d_in[13];
    const float* bl1    = (const float*)d_in[14];
    const float* Wi2    = (const float*)d_in[15];
    const float* Wh2    = (const float*)d_in[16];
    const float* bl2    = (const float*)d_in[17];
    const float* Wp     = (const float*)d_in[18];
    const float* bp     = (const float*)d_in[19];
    float* out = (float*)d_out;
    (void)in_sizes; (void)n_in; (void)out_size; (void)ws_size;

    char* ws = (char*)d_ws;
    size_t off = 0;
    auto carve = [&](size_t bytes)->char* {
        char* p = ws + off;
        off += (bytes + 255) & ~(size_t)255;
        return p;
    };
    __half*    inputs_h = (__half*)   carve((size_t)BB*TENC*EE*2);
    __half*    pe_h     = (__half*)   carve((size_t)BB*TENC*AA*2);
    __half*    PIP      = (__half*)   carve((size_t)BB*TENC*NM*2);
    _Float16*  XS1h     = (_Float16*) carve((size_t)(TDEC+1)*BB*K1*2);
    _Float16*  XS2h     = (_Float16*) carve((size_t)2*BB*K2*2);
    _Float16*  WA       = (_Float16*) carve((size_t)GG*K2*2);   // W2T scratch, later reused as W1F
    _Float16*  WB       = (_Float16*) carve((size_t)GG*K1*2);   // W1T scratch
    _Float16*  W2F      = (_Float16*) carve((size_t)GG*K2*2);
    _Float16*  WqT      = (_Float16*) carve((size_t)AA*HH*2);
    _Float16*  WohT     = (_Float16*) carve((size_t)NM*HH*2);
    const int NBAR = 576 + 256*32;   // mailbox barrier uints
    unsigned int* bar   = (unsigned int*)carve((size_t)NBAR*4);
    float* Mloc = (float*)carve((size_t)31*AA*4);
    float* cbp  = (float*)carve((size_t)AA*4);
    _Float16* W1F = WA;   // alias: W2T dead once W2F is built

    // ---- one-time precompute (per launch) ----
    k_zero<<<(NBAR+255)/256,256,0,stream>>>((float*)bar, NBAR);               // barrier counters+mailboxes
    k_zero<<<(2*BB*K2/2+255)/256,256,0,stream>>>((float*)XS2h, 2*BB*K2/2);    // h1,h2 parity = 0
    k_zero<<<(BB*K1/2+255)/256,256,0,stream>>>((float*)XS1h, BB*K1/2);        // row t=0
    k_cvt_half<<<2048,256,0,stream>>>(inputs, inputs_h, BB*TENC*EE);
    k_proc_enc<<<BB*TENC,128,0,stream>>>(inputs, W_enc, pe_h);
    k_prenet<<<TDEC,256,0,stream>>>(pmels, pw1,pb1,pw2,pb2, XS1h);
    k_mloc<<<1,128,0,stream>>>(conv_w, conv_b, W_loc, Mloc, cbp);
    k_transpose2<<<dim3(GG/32, 1024/32),256,0,stream>>>(Wi2, WA, 1024, GG, K2, 0,    1);
    k_transpose2<<<dim3(GG/32, 1024/32),256,0,stream>>>(Wh2, WA, 1024, GG, K2, 1024, 1);
    k_wfrag<<<dim3(K2/128, GG/16),256,0,stream>>>(WA, W2F, K2);
    k_transpose2<<<dim3(GG/32,  768/32),256,0,stream>>>(Wi1, WB, 768,  GG, K1, 0,    1);
    k_transpose2<<<dim3(GG/32, 1024/32),256,0,stream>>>(Wh1, WB, 1024, GG, K1, 768,  1);
    k_wfrag<<<dim3(K1/128, GG/16),256,0,stream>>>(WB, W1F, K1);
    k_transpose2<<<dim3(AA/32, 1024/32),256,0,stream>>>(W_q, WqT, 1024, AA, HH, 0,   0);
    k_transpose2<<<dim3(3,     1024/32),256,0,stream>>>(Wp,  WohT, 1024, NM, HH, 0,  0);
    k_pip<<<BB*64,320,0,stream>>>(inputs, Wp + (size_t)HH*NM, PIP);

    // ---- persistent decode: ONE cooperative kernel, mailbox barrier ----
    {
        void* ka[17];
        ka[0]  = (void*)&XS1h;
        ka[1]  = (void*)&XS2h;
        ka[2]  = (void*)&W1F;
        ka[3]  = (void*)&W2F;
        ka[4]  = (void*)&bl1;
        ka[5]  = (void*)&bl2;
        ka[6]  = (void*)&WqT;
        ka[7]  = (void*)&cbp;
        ka[8]  = (void*)&Mloc;
        ka[9]  = (void*)&v_e;
        ka[10] = (void*)&pe_h;
        ka[11] = (void*)&inputs_h;
        ka[12] = (void*)&PIP;
        ka[13] = (void*)&WohT;
        ka[14] = (void*)&bp;
        ka[15] = (void*)&out;
        ka[16] = (void*)&bar;
        hipLaunchCooperativeKernel((const void*)k_decode, dim3(256), dim3(512),
                                   ka, 0, stream);
    }
}

// Round 6
// 11364.775 us; speedup vs baseline: 3.8592x; 1.0536x over previous
//
#include <hip/hip_runtime.h>
#include <hip/hip_fp16.h>

#define BB   32
#define TENC 256
#define EE   512
#define TDEC 200
#define NM   80
#define HH   1024
#define AA   128
#define GG   4096
#define K1   1792   // x(256)|ctx(512)|h1(1024)
#define K2   2048   // h1|h2

#define NGRP  16
#define GRPSZ 16    // 256 blocks / 16 groups

typedef _Float16 h8v  __attribute__((ext_vector_type(8)));
typedef float    f32x4 __attribute__((ext_vector_type(4)));

__device__ __forceinline__ float sigf(float x){ return 1.0f/(1.0f + __expf(-x)); }
__device__ __forceinline__ float tanhfast(float x){ return 1.0f - 2.0f/(1.0f + __expf(2.0f*x)); }

__device__ __forceinline__ unsigned short h2b(float f){
    _Float16 h = (_Float16)f; unsigned short u; __builtin_memcpy(&u, &h, 2); return u;
}
__device__ __forceinline__ void st64(unsigned long long* p, unsigned long long v){
    __hip_atomic_store(p, v, __ATOMIC_RELAXED, __HIP_MEMORY_SCOPE_AGENT);
}
__device__ __forceinline__ void st32(unsigned int* p, unsigned int v){
    __hip_atomic_store(p, v, __ATOMIC_RELAXED, __HIP_MEMORY_SCOPE_AGENT);
}
__device__ __forceinline__ unsigned long long ld64(const unsigned long long* p){
    return __hip_atomic_load(p, __ATOMIC_RELAXED, __HIP_MEMORY_SCOPE_AGENT);
}
__device__ __forceinline__ unsigned int ld32(const unsigned int* p){
    return __hip_atomic_load(p, __ATOMIC_RELAXED, __HIP_MEMORY_SCOPE_AGENT);
}

// ---------------- precompute kernels ----------------

__global__ void k_zero(float* __restrict__ p, int n){
    int i = blockIdx.x*blockDim.x + threadIdx.x;
    if(i < n) p[i] = 0.f;
}

__global__ void k_cvt_half(const float* __restrict__ src, __half* __restrict__ dst, int n){
    int i = blockIdx.x*blockDim.x + threadIdx.x;
    int stride = gridDim.x*blockDim.x;
    for(; i<n; i+=stride) dst[i] = __float2half(src[i]);
}

// transpose fp32 src[k][c] -> fp16 dst[p][kOff+k]; pack=1 remaps c (gate*1024+cell) -> p=cell*4+gate
__global__ __launch_bounds__(256) void k_transpose2(const float* __restrict__ src,
                                                    _Float16* __restrict__ dst,
                                                    int K, int C, int dstStride, int kOff, int pack){
    __shared__ float tile[32][33];
    const int tid = threadIdx.x;
    const int c0 = blockIdx.x*32, k0 = blockIdx.y*32;
    const int cl = tid & 31, r8 = tid >> 5;
    #pragma unroll
    for(int i=0;i<4;i++){
        const int k = k0 + r8 + i*8;
        if(k < K && c0+cl < C) tile[r8 + i*8][cl] = src[(size_t)k*C + c0 + cl];
    }
    __syncthreads();
    const int kl = tid & 31, c8 = tid >> 5;
    #pragma unroll
    for(int i=0;i<4;i++){
        const int c = c0 + c8 + i*8;
        if(c < C && k0+kl < K){
            const int p = pack ? ((c & 1023)*4 + (c >> 10)) : c;
            dst[(size_t)p*dstStride + kOff + k0 + kl] = (_Float16)tile[kl][c8 + i*8];
        }
    }
}

// Rearrange WT fp16 [P=4096][K] into MFMA B-fragment order.
__global__ __launch_bounds__(256) void k_wfrag(const _Float16* __restrict__ WT,
                                               _Float16* __restrict__ WF, int K){
    const int tid = threadIdx.x;
    const int l = tid & 63, f = tid >> 6;
    const int ct = blockIdx.y;
    const int kc = blockIdx.x*4 + f;
    const h8v v = *(const h8v*)(WT + (size_t)(ct*16 + (l & 15))*K + kc*32 + ((l >> 4) << 3));
    *(h8v*)(WF + ((size_t)(ct*(K >> 5) + kc)*64 + l)*8) = v;
}

__global__ __launch_bounds__(128) void k_proc_enc(const float* __restrict__ inputs,
                                                  const float* __restrict__ Wenc,
                                                  __half* __restrict__ pe_h){
    const int row = blockIdx.x;
    const int a   = threadIdx.x;
    const float* in = inputs + (size_t)row*EE;
    float acc = 0.f;
    for(int k=0;k<EE;k++) acc = fmaf(in[k], Wenc[k*AA + a], acc);
    pe_h[(size_t)row*AA + a] = __float2half(acc);
}

__global__ __launch_bounds__(320) void k_pip(const float* __restrict__ inputs,
                                             const float* __restrict__ Wp_c,
                                             __half* __restrict__ PIP){
    const int b = blockIdx.x >> 6, t4 = (blockIdx.x & 63)*4;
    __shared__ float xs[4*EE];
    const int tid = threadIdx.x;
    for(int i=tid; i<4*EE; i+=320) xs[i] = inputs[((size_t)b*TENC + t4)*EE + i];
    __syncthreads();
    const int tl = tid/80, m = tid%80;
    float acc = 0.f;
    for(int k=0;k<EE;k++) acc = fmaf(xs[tl*EE + k], Wp_c[k*NM + m], acc);
    PIP[((size_t)b*TENC + t4 + tl)*NM + m] = __float2half(acc);
}

// prenet for all t -> fp16 XS1h rows [t][b][0:256] (row stride K1)
__global__ __launch_bounds__(256) void k_prenet(const float* __restrict__ pmels,
                                                const float* __restrict__ pw1, const float* __restrict__ pb1,
                                                const float* __restrict__ pw2, const float* __restrict__ pb2,
                                                _Float16* __restrict__ XS1h){
    const int t = blockIdx.x;
    __shared__ float pm[BB*NM];
    __shared__ float h1s[BB*256];
    const int tid = threadIdx.x;
    for(int el=tid; el<BB*NM; el+=256){
        const int b = el/NM, m = el%NM;
        pm[el] = (t==0) ? 0.f : pmels[(size_t)(b*NM + m)*TDEC + (t-1)];
    }
    __syncthreads();
    const int a = tid;
    float acc[BB];
    #pragma unroll
    for(int b=0;b<BB;b++) acc[b]=0.f;
    for(int m=0;m<NM;m++){
        const float w = pw1[m*256 + a];
        #pragma unroll
        for(int b=0;b<BB;b++) acc[b] = fmaf(pm[b*NM+m], w, acc[b]);
    }
    {
        const float bias = pb1[a];
        for(int b=0;b<BB;b++) h1s[b*256+a] = fmaxf(acc[b]+bias, 0.f);
    }
    __syncthreads();
    #pragma unroll
    for(int b=0;b<BB;b++) acc[b]=0.f;
    for(int k=0;k<256;k++){
        const float w = pw2[k*256 + a];
        #pragma unroll
        for(int b=0;b<BB;b++) acc[b] = fmaf(h1s[b*256+k], w, acc[b]);
    }
    {
        const float bias = pb2[a];
        #pragma unroll
        for(int b=0;b<BB;b++)
            XS1h[((size_t)t*BB + b)*K1 + a] = (_Float16)fmaxf(acc[b]+bias, 0.f);
    }
}

__global__ void k_mloc(const float* __restrict__ conv_w, const float* __restrict__ conv_b,
                       const float* __restrict__ W_loc, float* __restrict__ Mloc, float* __restrict__ cbp){
    const int a = threadIdx.x;
    for(int d=0; d<31; d++){
        float s = 0.f;
        for(int ch=0; ch<32; ch++) s = fmaf(conv_w[ch*31 + d], W_loc[ch*AA + a], s);
        Mloc[d*AA + a] = s;
    }
    float s = 0.f;
    for(int ch=0; ch<32; ch++) s = fmaf(conv_b[ch], W_loc[ch*AA + a], s);
    cbp[a] = s;
}

// ---------------- persistent decode kernel ----------------

// Mailbox grid barrier, relaxed-only atomics, 4-hop chain:
// subadd -> masteradd -> relay-detect(master) -> mailbox -> member-detect.
__device__ __forceinline__ void gridbar(unsigned int* bb, unsigned int bi, int tid, int bid, int& dead){
    __syncthreads();
    if(tid == 0){
        const int g = bid >> 4;
        unsigned int v = __hip_atomic_fetch_add(&bb[g*32], 1u, __ATOMIC_RELAXED, __HIP_MEMORY_SCOPE_AGENT);
        if(v == bi*GRPSZ - 1u)
            __hip_atomic_fetch_add(&bb[512], 1u, __ATOMIC_RELAXED, __HIP_MEMORY_SCOPE_AGENT);
        if(!dead){
            unsigned int guard = 0;
            if((bid & 15) == 0){
                while(ld32(&bb[512]) < bi*NGRP){
                    __builtin_amdgcn_s_sleep(2);
                    if(++guard > 3000000u){ dead = 1; break; }   // failsafe: no hang
                }
                #pragma unroll
                for(int m=1; m<GRPSZ; m++) st32(&bb[576 + (bid+m)*32], bi);
            } else {
                while(ld32(&bb[576 + bid*32]) < bi){
                    __builtin_amdgcn_s_sleep(2);
                    if(++guard > 3000000u){ dead = 1; break; }
                }
            }
        }
    }
    __syncthreads();
}

// One K-window of the packed GEMM: LF frags of 32 for this wave, both 16-row M-tiles.
// aCol: row0 of the window at this wave's first frag column. bWave: lane-resolved B ptr.
// AGENT: A through LLC (parity-addressed h2 buffers).
template<int LF, bool AGENT>
__device__ __forceinline__ void gemm_win(f32x4& accL, f32x4& accH,
    const _Float16* __restrict__ aCol, int strideA,
    const _Float16* __restrict__ bWave, int l)
{
    const int r = l & 15;
    const _Float16* a0 = aCol + (size_t)r*strideA + ((l >> 4) << 3);
    #pragma unroll
    for(int j=0;j<LF;j++){
        const h8v b8 = *(const h8v*)(bWave + (size_t)j*512);
        h8v aL, aH;
        if constexpr(AGENT){
            union { unsigned long long u[2]; h8v v; } uL, uH;
            const unsigned long long* pL = (const unsigned long long*)(a0 + j*32);
            const unsigned long long* pH = (const unsigned long long*)(a0 + (size_t)16*strideA + j*32);
            uL.u[0] = ld64(pL);   uL.u[1] = ld64(pL+1);
            uH.u[0] = ld64(pH);   uH.u[1] = ld64(pH+1);
            aL = uL.v; aH = uH.v;
        } else {
            aL = *(const h8v*)(a0 + j*32);
            aH = *(const h8v*)(a0 + (size_t)16*strideA + j*32);
        }
        accL = __builtin_amdgcn_mfma_f32_16x16x32_f16(aL, b8, accL, 0, 0, 0);
        accH = __builtin_amdgcn_mfma_f32_16x16x32_f16(aH, b8, accH, 0, 0, 0);
    }
}

// Cross-wave reduce + LSTM cell nonlinearity + packed fp16 h write (agent).
__device__ __forceinline__ void lstm_finish(
    const f32x4& accL, const f32x4& accH,
    const float* __restrict__ bias, float& cv,
    _Float16* __restrict__ hDst, int strideH,
    float* part, float* stage, int tid, int bid, int l, int kw)
{
    {
        const int r0 = (l >> 4) << 2, c = l & 15;
        #pragma unroll
        for(int j=0;j<4;j++){
            part[(kw*32 + r0 + j)*18 + c]      = accL[j];
            part[(kw*32 + 16 + r0 + j)*18 + c] = accH[j];
        }
    }
    __syncthreads();
    if(tid < 128){
        const int b = tid & 31, cl = tid >> 5;
        float g[4];
        #pragma unroll
        for(int gi=0; gi<4; gi++){
            const int c2 = cl*4 + gi;
            float s = 0.f;
            #pragma unroll
            for(int q=0;q<8;q++) s += part[(q*32 + b)*18 + c2];
            const int p = bid*16 + c2;           // packed col = cell*4 + gate
            g[gi] = s + bias[(p & 3)*HH + (p >> 2)];
        }
        const float cn = sigf(g[1])*cv + sigf(g[0])*tanhfast(g[2]);
        cv = cn;
        stage[tid] = sigf(g[3])*tanhfast(cn);    // stage[cl*32+b]
    }
    __syncthreads();
    if(tid < 32){
        const int b = tid;
        unsigned long long pk =
              (unsigned long long)h2b(stage[0*32+b])
            | ((unsigned long long)h2b(stage[1*32+b]) << 16)
            | ((unsigned long long)h2b(stage[2*32+b]) << 32)
            | ((unsigned long long)h2b(stage[3*32+b]) << 48);
        st64((unsigned long long*)(hDst + (size_t)b*strideH + bid*4), pk);
    }
}

__global__ __launch_bounds__(512) void k_decode(
    _Float16* __restrict__ XS1h, _Float16* __restrict__ H2P,
    const _Float16* __restrict__ W1F, const _Float16* __restrict__ W2F,
    const float* __restrict__ bl1, const float* __restrict__ bl2,
    const _Float16* __restrict__ WqT, const float* __restrict__ cbp,
    const float* __restrict__ Mloc, const float* __restrict__ ve,
    const __half* __restrict__ pe,
    const __half* __restrict__ inputs_h, const __half* __restrict__ PIP,
    const _Float16* __restrict__ WohT, const float* __restrict__ bp,
    float* __restrict__ out, unsigned int* __restrict__ bar)
{
    const int tid = threadIdx.x, bid = blockIdx.x;
    const int l = tid & 63, kw = tid >> 6;

    __shared__ float s_ml[31*AA];
    __shared__ float s_ves[AA];
    __shared__ float s_part[8*32*18];    // lstm partials; aliased: attn ep (1024) / ctxred (4096)
    __shared__ float s_h2s[1024];
    __shared__ float s_qc[4*AA];
    __shared__ float s_qf[AA];           // also lstm h-staging (128)
    __shared__ float s_awin[288];
    __shared__ float s_aw[TENC];
    __shared__ float s_awc[TENC];        // persistent per-b cumulative attention (blocks 0..31)
    __shared__ float s_red1[320];
    __shared__ float s_red2[320];
    __shared__ float s_sred[8];

    for(int i=tid; i<31*AA; i+=512) s_ml[i] = Mloc[i];
    if(tid < AA) s_ves[tid] = ve[tid];
    if(bid < BB) for(int i=tid; i<TENC; i+=512) s_awc[i] = 0.f;
    __syncthreads();

    float c1v = 0.f, c2v = 0.f;          // cell state in registers (tid<128 own 4 cells x 32 b)
    int dead = 0;
    unsigned int bi = 0;

    const f32x4 z4 = {0.f,0.f,0.f,0.f};
    f32x4 p1L = z4, p1H = z4;            // LSTM1 partial (x|h1 windows), step t
    f32x4 p2L = z4, p2H = z4;            // LSTM2 partial (h2 window), step t

    // prologue: partials for step 0 (row0: x real, h1=0; H2P[1]=0)
    gemm_win<1,false>(p1L,p1H, XS1h + kw*32,        K1, W1F + ((size_t)(bid*56 + kw)*64 + l)*8, l);
    gemm_win<4,false>(p1L,p1H, XS1h + 768 + kw*128, K1, W1F + ((size_t)(bid*56 + 24 + kw*4)*64 + l)*8, l);
    gemm_win<4,true >(p2L,p2H, H2P + (size_t)BB*HH + kw*128, HH, W2F + ((size_t)(bid*64 + 32 + kw*4)*64 + l)*8, l);

    for(int t=0; t<TDEC; t++){
        _Float16* rowT  = XS1h + (size_t)t*BB*K1;
        _Float16* rowT1 = XS1h + (size_t)(t+1)*BB*K1;
        _Float16* h2cur = H2P + (size_t)(t & 1)*BB*HH;

        // ---- P1: LSTM1 ctx-part (K=512) + finish -> h1(t) into rowT1[768:1792] ----
        {
            f32x4 aL = p1L, aH = p1H;
            gemm_win<2,false>(aL,aH, rowT + 256 + kw*64, K1, W1F + ((size_t)(bid*56 + 8 + kw*2)*64 + l)*8, l);
            lstm_finish(aL,aH, bl1, c1v, rowT1 + 768, K1, s_part, s_qf, tid, bid, l, kw);
        }
        gridbar(bar, ++bi, tid, bid, dead);

        // ---- P2: LSTM2 h1-part (K=1024, normal cached reads of rowT1 h1) + finish -> h2(t) ----
        {
            f32x4 aL = p2L, aH = p2H;
            gemm_win<4,false>(aL,aH, rowT1 + 768 + kw*128, K1, W2F + ((size_t)(bid*64 + kw*4)*64 + l)*8, l);
            lstm_finish(aL,aH, bl2, c2v, h2cur, HH, s_part, s_qf, tid, bid, l, kw);
        }
        gridbar(bar, ++bi, tid, bid, dead);

        // ---- P3: next-step partials (all blocks) + attention (blocks 0..31) ----
        p1L = z4; p1H = z4; p2L = z4; p2H = z4;
        gemm_win<1,false>(p1L,p1H, rowT1 + kw*32,        K1, W1F + ((size_t)(bid*56 + kw)*64 + l)*8, l);
        gemm_win<4,false>(p1L,p1H, rowT1 + 768 + kw*128, K1, W1F + ((size_t)(bid*56 + 24 + kw*4)*64 + l)*8, l);
        gemm_win<4,true >(p2L,p2H, h2cur + kw*128,       HH, W2F + ((size_t)(bid*64 + 32 + kw*4)*64 + l)*8, l);

        if(bid < BB){
            const int b = bid;
            {   // h2(t) -> LDS fp32 (agent: parity addresses)
                const unsigned int* hp = (const unsigned int*)(h2cur + (size_t)b*HH);
                union { unsigned int u; _Float16 h[2]; } cu;
                cu.u = ld32(hp + tid);
                s_h2s[2*tid]   = (float)cu.h[0];
                s_h2s[2*tid+1] = (float)cu.h[1];
            }
            for(int i=tid; i<286; i+=512){
                const int g2 = i - 15;
                s_awin[i] = (g2>=0 && g2<TENC) ? s_awc[g2] : 0.f;
            }
            __syncthreads();
            {   // q[a] = h2 . WqT[a][:], K split 4 ways
                const int a = tid & 127, tp = tid >> 7;
                float qa = 0.f;
                const _Float16* wq = WqT + (size_t)a*HH + tp*256;
                const float* hs = s_h2s + tp*256;
                for(int kb=0; kb<256; kb+=8){
                    const h8v w8 = *(const h8v*)(wq + kb);
                    #pragma unroll
                    for(int i2=0;i2<8;i2++) qa = fmaf((float)w8[i2], hs[kb+i2], qa);
                }
                s_qc[tp*AA + a] = qa;
            }
            __syncthreads();
            if(tid < AA) s_qf[tid] = s_qc[tid] + s_qc[AA+tid] + s_qc[2*AA+tid] + s_qc[3*AA+tid] + cbp[tid];
            __syncthreads();
            // energies: (ti = t-index, ah = 32-wide a-block), 2 outer iters cover ah 0..3
            float* s_ep = s_part;
            #pragma unroll
            for(int it=0; it<2; it++){
                const int ti = tid & 255, ah = (tid >> 8) + 2*it;
                const int a0 = ah*32;
                float s[32];
                const h8v* pp = (const h8v*)((const _Float16*)pe + ((size_t)(b*TENC + ti))*AA + a0);
                #pragma unroll
                for(int vq=0; vq<4; vq++){
                    const h8v pv = pp[vq];
                    #pragma unroll
                    for(int j=0;j<8;j++) s[vq*8+j] = s_qf[a0+vq*8+j] + (float)pv[j];
                }
                for(int d=0; d<31; d++){
                    const float w = s_awin[ti+d];
                    #pragma unroll
                    for(int j=0;j<32;j++) s[j] = fmaf(w, s_ml[d*AA + a0 + j], s[j]);
                }
                float es = 0.f;
                #pragma unroll
                for(int j=0;j<32;j++) es = fmaf(tanhfast(s[j]), s_ves[a0+j], es);
                s_ep[ah*256 + ti] = es;
            }
            __syncthreads();
            // softmax over 256 energies
            float e = -1e30f;
            if(tid < 256) e = s_ep[tid] + s_ep[256+tid] + s_ep[512+tid] + s_ep[768+tid];
            float m_ = e;
            #pragma unroll
            for(int o=32;o>=1;o>>=1) m_ = fmaxf(m_, __shfl_xor(m_, o));
            if((tid&63)==0 && tid<256) s_sred[tid>>6] = m_;
            __syncthreads();
            const float mm = fmaxf(fmaxf(s_sred[0],s_sred[1]), fmaxf(s_sred[2],s_sred[3]));
            const float pv2 = (tid<256) ? __expf(e - mm) : 0.f;
            float sum = pv2;
            #pragma unroll
            for(int o=32;o>=1;o>>=1) sum += __shfl_xor(sum, o);
            if((tid&63)==0 && tid<256) s_sred[4+(tid>>6)] = sum;
            __syncthreads();
            sum = s_sred[4]+s_sred[5]+s_sred[6]+s_sred[7];
            if(tid < 256){
                const float awv = pv2/sum;
                s_aw[tid] = awv;
                s_awc[tid] += awv;
            }
            __syncthreads();
            // ctx: (ch8 = 8 channels, tq = t-slice of 8) + LDS reduce
            float* ctxred = s_part;
            {
                const int ch8 = tid & 63, tq = tid >> 6;
                const _Float16* ib = (const _Float16*)inputs_h + (size_t)b*TENC*EE + ch8*8;
                float a_[8];
                #pragma unroll
                for(int j=0;j<8;j++) a_[j]=0.f;
                for(int tt=tq; tt<TENC; tt+=8){
                    const float wv = s_aw[tt];
                    const h8v x8 = *(const h8v*)(ib + (size_t)tt*EE);
                    #pragma unroll
                    for(int j=0;j<8;j++) a_[j] = fmaf(wv, (float)x8[j], a_[j]);
                }
                #pragma unroll
                for(int j=0;j<8;j++) ctxred[tq*512 + ch8*8 + j] = a_[j];
            }
            __syncthreads();
            if(tid < 256){   // ctx -> rowT1[256:768] (paired agent 4B stores)
                const int ch = 2*tid;
                float s0=0.f, s1=0.f;
                #pragma unroll
                for(int q=0;q<8;q++){ s0 += ctxred[q*512 + ch]; s1 += ctxred[q*512 + ch + 1]; }
                union { unsigned int u; _Float16 h[2]; } cu;
                cu.h[0] = (_Float16)s0; cu.h[1] = (_Float16)s1;
                st32((unsigned int*)(rowT1 + (size_t)b*K1 + 256) + tid, cu.u);
            }
            if(tid < 320){   // output projection: s1 = h2 @ WohT, s2 = aw . PIP (K quarters)
                const int m2 = tid % 80, kh = tid / 80;
                float s1 = 0.f;
                const _Float16* wo = WohT + (size_t)m2*HH + kh*256;
                const float* hs = s_h2s + kh*256;
                for(int kb=0; kb<256; kb+=8){
                    const h8v w8 = *(const h8v*)(wo + kb);
                    #pragma unroll
                    for(int i2=0;i2<8;i2++) s1 = fmaf((float)w8[i2], hs[kb+i2], s1);
                }
                s_red1[kh*80 + m2] = s1;
                float s2 = 0.f;
                const __half* pp2 = PIP + ((size_t)(b*TENC) + kh*64)*NM + m2;
                const float* awp = s_aw + kh*64;
                for(int tt=0; tt<64; tt++)
                    s2 = fmaf(awp[tt], __half2float(pp2[(size_t)tt*NM]), s2);
                s_red2[kh*80 + m2] = s2;
            }
            __syncthreads();
            if(tid < NM){
                const float o = s_red1[tid]+s_red1[80+tid]+s_red1[160+tid]+s_red1[240+tid]
                              + s_red2[tid]+s_red2[80+tid]+s_red2[160+tid]+s_red2[240+tid] + bp[tid];
                out[((size_t)t*BB + b)*NM + tid] = o;
            }
        }
        gridbar(bar, ++bi, tid, bid, dead);
    }
}

// ---------------- host ----------------

extern "C" void kernel_launch(void* const* d_in, const int* in_sizes, int n_in,
                              void* d_out, int out_size, void* d_ws, size_t ws_size,
                              hipStream_t stream)
{
    const float* inputs = (const float*)d_in[0];
    const float* pmels  = (const float*)d_in[1];
    const float* W_enc  = (const float*)d_in[2];
    const float* W_q    = (const float*)d_in[3];
    const float* conv_w = (const float*)d_in[4];
    const float* conv_b = (const float*)d_in[5];
    const float* W_loc  = (const float*)d_in[6];
    const float* v_e    = (const float*)d_in[7];
    const float* pw1    = (const float*)d_in[8];
    const float* pb1    = (const float*)d_in[9];
    const float* pw2    = (const float*)d_in[10];
    const float* pb2    = (const float*)d_in[11];
    const float* Wi1    = (const float*)d_in[12];
    const float* Wh1    = (const float*)d_in[13];
    const float* bl1    = (const float*)d_in[14];
    const float* Wi2    = (const float*)d_in[15];
    const float* Wh2    = (const float*)d_in[16];
    const float* bl2    = (const float*)d_in[17];
    const float* Wp     = (const float*)d_in[18];
    const float* bp     = (const float*)d_in[19];
    float* out = (float*)d_out;
    (void)in_sizes; (void)n_in; (void)out_size; (void)ws_size;

    char* ws = (char*)d_ws;
    size_t off = 0;
    auto carve = [&](size_t bytes)->char* {
        char* p = ws + off;
        off += (bytes + 255) & ~(size_t)255;
        return p;
    };
    __half*    inputs_h = (__half*)   carve((size_t)BB*TENC*EE*2);
    __half*    pe_h     = (__half*)   carve((size_t)BB*TENC*AA*2);
    __half*    PIP      = (__half*)   carve((size_t)BB*TENC*NM*2);
    _Float16*  XS1h     = (_Float16*) carve((size_t)(TDEC+1)*BB*K1*2);
    _Float16*  H2P      = (_Float16*) carve((size_t)2*BB*HH*2);
    _Float16*  WA       = (_Float16*) carve((size_t)GG*K2*2);   // W2T scratch, later reused as W1F
    _Float16*  WB       = (_Float16*) carve((size_t)GG*K1*2);   // W1T scratch
    _Float16*  W2F      = (_Float16*) carve((size_t)GG*K2*2);
    _Float16*  WqT      = (_Float16*) carve((size_t)AA*HH*2);
    _Float16*  WohT     = (_Float16*) carve((size_t)NM*HH*2);
    const int NBAR = 576 + 256*32;   // mailbox barrier uints
    unsigned int* bar   = (unsigned int*)carve((size_t)NBAR*4);
    float* Mloc = (float*)carve((size_t)31*AA*4);
    float* cbp  = (float*)carve((size_t)AA*4);
    _Float16* W1F = WA;   // alias: W2T dead once W2F is built

    // ---- one-time precompute (per launch) ----
    k_zero<<<(NBAR+255)/256,256,0,stream>>>((float*)bar, NBAR);               // barrier counters+mailboxes
    k_zero<<<(2*BB*HH/2+255)/256,256,0,stream>>>((float*)H2P, 2*BB*HH/2);     // h2 parity = 0
    k_zero<<<(BB*K1/2+255)/256,256,0,stream>>>((float*)XS1h, BB*K1/2);        // row t=0
    k_cvt_half<<<2048,256,0,stream>>>(inputs, inputs_h, BB*TENC*EE);
    k_proc_enc<<<BB*TENC,128,0,stream>>>(inputs, W_enc, pe_h);
    k_prenet<<<TDEC,256,0,stream>>>(pmels, pw1,pb1,pw2,pb2, XS1h);
    k_mloc<<<1,128,0,stream>>>(conv_w, conv_b, W_loc, Mloc, cbp);
    k_transpose2<<<dim3(GG/32, 1024/32),256,0,stream>>>(Wi2, WA, 1024, GG, K2, 0,    1);
    k_transpose2<<<dim3(GG/32, 1024/32),256,0,stream>>>(Wh2, WA, 1024, GG, K2, 1024, 1);
    k_wfrag<<<dim3(K2/128, GG/16),256,0,stream>>>(WA, W2F, K2);
    k_transpose2<<<dim3(GG/32,  768/32),256,0,stream>>>(Wi1, WB, 768,  GG, K1, 0,    1);
    k_transpose2<<<dim3(GG/32, 1024/32),256,0,stream>>>(Wh1, WB, 1024, GG, K1, 768,  1);
    k_wfrag<<<dim3(K1/128, GG/16),256,0,stream>>>(WB, W1F, K1);
    k_transpose2<<<dim3(AA/32, 1024/32),256,0,stream>>>(W_q, WqT, 1024, AA, HH, 0,   0);
    k_transpose2<<<dim3(3,     1024/32),256,0,stream>>>(Wp,  WohT, 1024, NM, HH, 0,  0);
    k_pip<<<BB*64,320,0,stream>>>(inputs, Wp + (size_t)HH*NM, PIP);

    // ---- persistent decode: ONE cooperative kernel, mailbox barrier ----
    {
        void* ka[17];
        ka[0]  = (void*)&XS1h;
        ka[1]  = (void*)&H2P;
        ka[2]  = (void*)&W1F;
        ka[3]  = (void*)&W2F;
        ka[4]  = (void*)&bl1;
        ka[5]  = (void*)&bl2;
        ka[6]  = (void*)&WqT;
        ka[7]  = (void*)&cbp;
        ka[8]  = (void*)&Mloc;
        ka[9]  = (void*)&v_e;
        ka[10] = (void*)&pe_h;
        ka[11] = (void*)&inputs_h;
        ka[12] = (void*)&PIP;
        ka[13] = (void*)&WohT;
        ka[14] = (void*)&bp;
        ka[15] = (void*)&out;
        ka[16] = (void*)&bar;
        hipLaunchCooperativeKernel((const void*)k_decode, dim3(256), dim3(512),
                                   ka, 0, stream);
    }
}